// Round 1
// baseline (393.351 us; speedup 1.0000x reference)
//
#include <hip/hip_runtime.h>
#include <math.h>

// Problem constants (from setup_inputs): B=2, L=2048, H=8, D=64, M=128.
constexpr int B_ = 2, L_ = 2048, H_ = 8, D_ = 64, M_ = 128;
constexpr int T_ = 64;            // chunk length for the parallel scan
constexpr int C_ = L_ / T_;       // 32 chunks
constexpr int POS_ = 16;          // positions per feature-map block
constexpr float DN_ = 0.35355339059327373f;     // 64^-0.25
constexpr float RATIO_ = 0.08838834764831845f;  // 1/sqrt(128)
constexpr float EPSV_ = 1e-6f;

__device__ inline void atomicMaxFloat(float* addr, float val) {
  // standard signed trick: works for mixed signs, init must be -inf
  if (val >= 0.f) atomicMax((int*)addr, __float_as_int(val));
  else atomicMin((unsigned int*)addr, __float_as_uint(val));
}

__global__ void init_kmax_kernel(float* kmax) {
  if (threadIdx.x < B_ * H_) kmax[threadIdx.x] = -INFINITY;
}

// Feature map: computes data_dash rows for POS_ consecutive l of one (b,h).
// IS_Q: per-position stab (max over m), write q' directly.
// !IS_Q: write raw dash + diag, atomicMax per-(b,h) running max (exp pass later).
template <bool IS_Q>
__global__ __launch_bounds__(128) void feat_kernel(
    const float* __restrict__ x, const float* __restrict__ P,
    float* __restrict__ outp, float* __restrict__ diag_out,
    float* __restrict__ kmax) {
  __shared__ __align__(16) float x_s[POS_][D_];
  __shared__ float diag_s[POS_];
  __shared__ float wred_s[2][POS_];
  const int nlt = L_ / POS_;
  const int bid = blockIdx.x;
  const int lt = bid % nlt;
  const int h = (bid / nlt) % H_;
  const int b = bid / (nlt * H_);
  const int bh = b * H_ + h;
  const int tid = threadIdx.x;  // m index

  for (int i = tid; i < POS_ * D_; i += 128) {
    const int pos = i >> 6, d = i & 63;
    const int l = lt * POS_ + pos;
    x_s[pos][d] = DN_ * x[((size_t)(b * L_ + l) * H_ + h) * D_ + d];
  }
  __syncthreads();
  if (tid < POS_) {
    float s = 0.f;
#pragma unroll
    for (int d = 0; d < D_; ++d) { const float q = x_s[tid][d]; s += q * q; }
    diag_s[tid] = 0.5f * s;
  }
  // projection row m -> registers
  float p[D_];
  {
    const float* Pr = P + tid * D_;
#pragma unroll
    for (int d = 0; d < D_; d += 4) {
      const float4 t4 = *reinterpret_cast<const float4*>(Pr + d);
      p[d] = t4.x; p[d + 1] = t4.y; p[d + 2] = t4.z; p[d + 3] = t4.w;
    }
  }
  __syncthreads();  // diag_s ready

  float acc[POS_];
#pragma unroll
  for (int pos = 0; pos < POS_; ++pos) {
    float s = 0.f;
#pragma unroll
    for (int d = 0; d < D_; d += 4) {
      const float4 qv = *reinterpret_cast<const float4*>(&x_s[pos][d]);
      s += qv.x * p[d] + qv.y * p[d + 1] + qv.z * p[d + 2] + qv.w * p[d + 3];
    }
    acc[pos] = s;
  }
  const int wave = tid >> 6, lane = tid & 63;
  if (IS_Q) {
#pragma unroll
    for (int pos = 0; pos < POS_; ++pos) {
      float v = acc[pos];
      for (int off = 32; off; off >>= 1) v = fmaxf(v, __shfl_xor(v, off, 64));
      if (lane == 0) wred_s[wave][pos] = v;
    }
    __syncthreads();
#pragma unroll
    for (int pos = 0; pos < POS_; ++pos) {
      const float stab = fmaxf(wred_s[0][pos], wred_s[1][pos]);
      const float val = RATIO_ * (expf(acc[pos] - diag_s[pos] - stab) + EPSV_);
      const int l = lt * POS_ + pos;
      outp[((size_t)bh * L_ + l) * M_ + tid] = val;
    }
  } else {
    float bm = -INFINITY;
#pragma unroll
    for (int pos = 0; pos < POS_; ++pos) bm = fmaxf(bm, acc[pos]);
    for (int off = 32; off; off >>= 1) bm = fmaxf(bm, __shfl_xor(bm, off, 64));
    if (lane == 0) wred_s[wave][0] = bm;
    __syncthreads();
    if (tid == 0) atomicMaxFloat(&kmax[bh], fmaxf(wred_s[0][0], wred_s[1][0]));
#pragma unroll
    for (int pos = 0; pos < POS_; ++pos) {
      const int l = lt * POS_ + pos;
      outp[((size_t)bh * L_ + l) * M_ + tid] = acc[pos];  // raw dash
    }
    if (tid < POS_) diag_out[(size_t)bh * L_ + lt * POS_ + tid] = diag_s[tid];
  }
}

// Elementwise: kp = ratio*(exp(dash - diag - kmax_bh) + eps), in place.
__global__ __launch_bounds__(256) void kexp_kernel(
    float* __restrict__ kp, const float* __restrict__ kdiag,
    const float* __restrict__ kmax) {
  const int idx4 = blockIdx.x * 256 + threadIdx.x;  // over (B*H*L*M)/4
  const int bh = idx4 >> 16;           // L*M/4 = 65536 per bh
  const int l = (idx4 >> 5) & (L_ - 1);
  float4 v = *reinterpret_cast<float4*>(kp + (size_t)idx4 * 4);
  const float sub = kdiag[(size_t)bh * L_ + l] + kmax[bh];
  v.x = RATIO_ * (expf(v.x - sub) + EPSV_);
  v.y = RATIO_ * (expf(v.y - sub) + EPSV_);
  v.z = RATIO_ * (expf(v.z - sub) + EPSV_);
  v.w = RATIO_ * (expf(v.w - sub) + EPSV_);
  *reinterpret_cast<float4*>(kp + (size_t)idx4 * 4) = v;
}

// Per-chunk local sums: KV_c[m][d] = sum_t kp[t][m]*v[t][d];  ks_c[m] = sum_t kp[t][m]
__global__ __launch_bounds__(256) void chunk_sum_kernel(
    const float* __restrict__ kp, const float* __restrict__ v,
    float* __restrict__ kvc, float* __restrict__ ksc) {
  __shared__ __align__(16) float kp_s[T_][M_];  // 32KB
  __shared__ __align__(16) float v_s[T_][D_];   // 16KB
  const int bid = blockIdx.x;
  const int c = bid % C_, bh = bid / C_;
  const int b = bh >> 3, h = bh & 7;
  const int tid = threadIdx.x;
  const float* kpt = kp + ((size_t)bh * L_ + c * T_) * M_;
  for (int i4 = tid; i4 < T_ * M_ / 4; i4 += 256)
    *reinterpret_cast<float4*>(&kp_s[0][0] + i4 * 4) =
        *reinterpret_cast<const float4*>(kpt + i4 * 4);
  for (int i4 = tid; i4 < T_ * D_ / 4; i4 += 256) {
    const int t = i4 >> 4, d0 = (i4 & 15) * 4;
    *reinterpret_cast<float4*>(&v_s[t][d0]) = *reinterpret_cast<const float4*>(
        &v[((size_t)(b * L_ + c * T_ + t) * H_ + h) * D_ + d0]);
  }
  __syncthreads();
  const int mg = tid >> 3;  // m base = mg*4
  const int dg = tid & 7;   // d base = dg*8
  float acc[4][8];
#pragma unroll
  for (int i = 0; i < 4; ++i)
#pragma unroll
    for (int j = 0; j < 8; ++j) acc[i][j] = 0.f;
  for (int t = 0; t < T_; ++t) {
    const float4 a4 = *reinterpret_cast<const float4*>(&kp_s[t][mg * 4]);
    const float4 v0 = *reinterpret_cast<const float4*>(&v_s[t][dg * 8]);
    const float4 v1 = *reinterpret_cast<const float4*>(&v_s[t][dg * 8 + 4]);
    const float a[4] = {a4.x, a4.y, a4.z, a4.w};
    const float vv[8] = {v0.x, v0.y, v0.z, v0.w, v1.x, v1.y, v1.z, v1.w};
#pragma unroll
    for (int i = 0; i < 4; ++i)
#pragma unroll
      for (int j = 0; j < 8; ++j) acc[i][j] += a[i] * vv[j];
  }
  float* outb = kvc + (size_t)(bh * C_ + c) * M_ * D_;
#pragma unroll
  for (int i = 0; i < 4; ++i) {
    float4 o0 = {acc[i][0], acc[i][1], acc[i][2], acc[i][3]};
    float4 o1 = {acc[i][4], acc[i][5], acc[i][6], acc[i][7]};
    *reinterpret_cast<float4*>(&outb[(mg * 4 + i) * D_ + dg * 8]) = o0;
    *reinterpret_cast<float4*>(&outb[(mg * 4 + i) * D_ + dg * 8 + 4]) = o1;
  }
  if (tid < M_) {
    float s = 0.f;
    for (int t = 0; t < T_; ++t) s += kp_s[t][tid];
    ksc[(size_t)(bh * C_ + c) * M_ + tid] = s;
  }
}

// Convert per-chunk sums to EXCLUSIVE prefix sums across chunks (in place).
__global__ __launch_bounds__(256) void prefix_kernel(float* __restrict__ kvc,
                                                     float* __restrict__ ksc) {
  const int bid = blockIdx.x;  // B*H*32
  const int ej = bid & 31, bh = bid >> 5;
  const int e = ej * 256 + threadIdx.x;  // 0..8191 element of [M][D]
  float run = 0.f;
  for (int c = 0; c < C_; ++c) {
    const size_t idx = (size_t)(bh * C_ + c) * (M_ * D_) + e;
    const float t = kvc[idx];
    kvc[idx] = run;
    run += t;
  }
  if (ej == 0 && threadIdx.x < M_) {
    float rs = 0.f;
    const int m = threadIdx.x;
    for (int c = 0; c < C_; ++c) {
      const size_t idx = (size_t)(bh * C_ + c) * M_ + m;
      const float t = ksc[idx];
      ksc[idx] = rs;
      rs += t;
    }
  }
}

// Intra-chunk: S = Qp Kp^T (tril-masked), num = S_m V + Qp KVprefix,
// den = rowsum(S_m) + Qp . ksprefix;  out = num/den.
__global__ __launch_bounds__(256) void intra_kernel(
    const float* __restrict__ qp, const float* __restrict__ kp,
    const float* __restrict__ v, const float* __restrict__ kvp,
    const float* __restrict__ ksp, float* __restrict__ out) {
  __shared__ __align__(16) float smem[3 * T_ * 68 + M_ + T_];  // ~53KB
  float* bufA = smem;                // qp slices; later aliased as v tile
  float* bufB = smem + T_ * 68;      // kp slices; later KVprefix slices
  float* S_s = smem + 2 * T_ * 68;   // masked S
  float* ksp_s = smem + 3 * T_ * 68;
  float* den_s = ksp_s + M_;

  const int bid = blockIdx.x;
  const int c = bid % C_, bh = bid / C_;
  const int b = bh >> 3, h = bh & 7;
  const int tid = threadIdx.x;
  const int tr = tid >> 4, tc = tid & 15;
  const int r0 = tr * 4, c0 = tc * 4;

  const float* qpt = qp + ((size_t)bh * L_ + c * T_) * M_;
  const float* kpt = kp + ((size_t)bh * L_ + c * T_) * M_;

  float acc[4][4];
#pragma unroll
  for (int i = 0; i < 4; ++i)
#pragma unroll
    for (int j = 0; j < 4; ++j) acc[i][j] = 0.f;

  // Phase 1: S = qp @ kp^T over M in 2 slices of 64
  for (int ks = 0; ks < 2; ++ks) {
    if (ks) __syncthreads();
    for (int i4 = tid; i4 < T_ * 16; i4 += 256) {
      const int t = i4 >> 4, d0 = (i4 & 15) * 4;
      *reinterpret_cast<float4*>(&bufA[t * 68 + d0]) =
          *reinterpret_cast<const float4*>(&qpt[t * M_ + ks * 64 + d0]);
      *reinterpret_cast<float4*>(&bufB[t * 68 + d0]) =
          *reinterpret_cast<const float4*>(&kpt[t * M_ + ks * 64 + d0]);
    }
    __syncthreads();
    for (int k4 = 0; k4 < 16; ++k4) {
      float4 qv[4], kv[4];
#pragma unroll
      for (int i = 0; i < 4; ++i)
        qv[i] = *reinterpret_cast<const float4*>(&bufA[(r0 + i) * 68 + k4 * 4]);
#pragma unroll
      for (int j = 0; j < 4; ++j)
        kv[j] = *reinterpret_cast<const float4*>(&bufB[(c0 + j) * 68 + k4 * 4]);
#pragma unroll
      for (int i = 0; i < 4; ++i)
#pragma unroll
        for (int j = 0; j < 4; ++j)
          acc[i][j] += qv[i].x * kv[j].x + qv[i].y * kv[j].y +
                       qv[i].z * kv[j].z + qv[i].w * kv[j].w;
    }
  }
  // mask + write S + den rowsum (reduced across tc in-register)
  float dpart[4];
#pragma unroll
  for (int i = 0; i < 4; ++i) {
    const int r = r0 + i;
    float s[4];
#pragma unroll
    for (int j = 0; j < 4; ++j) s[j] = (c0 + j <= r) ? acc[i][j] : 0.f;
    float4 sv = {s[0], s[1], s[2], s[3]};
    *reinterpret_cast<float4*>(&S_s[r * 68 + c0]) = sv;
    dpart[i] = s[0] + s[1] + s[2] + s[3];
  }
#pragma unroll
  for (int off = 1; off < 16; off <<= 1)
#pragma unroll
    for (int i = 0; i < 4; ++i) dpart[i] += __shfl_xor(dpart[i], off, 64);
  if (tc == 0) {
#pragma unroll
    for (int i = 0; i < 4; ++i) den_s[r0 + i] = dpart[i];
  }
  __syncthreads();  // phase-1 reads done; safe to overwrite bufA with V
  for (int i4 = tid; i4 < T_ * 16; i4 += 256) {
    const int t = i4 >> 4, d0 = (i4 & 15) * 4;
    *reinterpret_cast<float4*>(&bufA[t * 68 + d0]) =
        *reinterpret_cast<const float4*>(
            &v[((size_t)(b * L_ + c * T_ + t) * H_ + h) * D_ + d0]);
  }
  if (tid < M_) ksp_s[tid] = ksp[(size_t)(bh * C_ + c) * M_ + tid];
  __syncthreads();
#pragma unroll
  for (int i = 0; i < 4; ++i)
#pragma unroll
    for (int j = 0; j < 4; ++j) acc[i][j] = 0.f;
  // Phase 2a: num += S_masked @ V
  for (int k4 = 0; k4 < 16; ++k4) {
    float4 sv[4];
#pragma unroll
    for (int i = 0; i < 4; ++i)
      sv[i] = *reinterpret_cast<const float4*>(&S_s[(r0 + i) * 68 + k4 * 4]);
#pragma unroll
    for (int j = 0; j < 4; ++j) {
      const int tp = k4 * 4 + j;
      const float4 vv = *reinterpret_cast<const float4*>(&bufA[tp * 68 + c0]);
#pragma unroll
      for (int i = 0; i < 4; ++i) {
        const float sj = j == 0 ? sv[i].x : j == 1 ? sv[i].y
                       : j == 2 ? sv[i].z : sv[i].w;
        acc[i][0] += sj * vv.x; acc[i][1] += sj * vv.y;
        acc[i][2] += sj * vv.z; acc[i][3] += sj * vv.w;
      }
    }
  }
  // Phase 2b: num += qp @ KVprefix; den += qp . ksprefix
  float dden[4] = {0.f, 0.f, 0.f, 0.f};
  const float* kvpc = kvp + (size_t)(bh * C_ + c) * M_ * D_;
  for (int ks = 0; ks < 2; ++ks) {
    __syncthreads();
    for (int i4 = tid; i4 < T_ * 16; i4 += 256) {
      const int t = i4 >> 4, d0 = (i4 & 15) * 4;
      *reinterpret_cast<float4*>(&bufA[t * 68 + d0]) =
          *reinterpret_cast<const float4*>(&qpt[t * M_ + ks * 64 + d0]);
      *reinterpret_cast<float4*>(&bufB[t * 68 + d0]) =
          *reinterpret_cast<const float4*>(&kvpc[(ks * 64 + t) * D_ + d0]);
    }
    __syncthreads();
    for (int m4 = 0; m4 < 16; ++m4) {
      float4 qv[4];
#pragma unroll
      for (int i = 0; i < 4; ++i)
        qv[i] = *reinterpret_cast<const float4*>(&bufA[(r0 + i) * 68 + m4 * 4]);
#pragma unroll
      for (int j = 0; j < 4; ++j) {
        const int mrow = m4 * 4 + j;
        const float4 kvv = *reinterpret_cast<const float4*>(&bufB[mrow * 68 + c0]);
        const float km = ksp_s[ks * 64 + mrow];
#pragma unroll
        for (int i = 0; i < 4; ++i) {
          const float qj = j == 0 ? qv[i].x : j == 1 ? qv[i].y
                        : j == 2 ? qv[i].z : qv[i].w;
          dden[i] += qj * km;
          acc[i][0] += qj * kvv.x; acc[i][1] += qj * kvv.y;
          acc[i][2] += qj * kvv.z; acc[i][3] += qj * kvv.w;
        }
      }
    }
  }
  if (tc == 0) {
#pragma unroll
    for (int i = 0; i < 4; ++i) den_s[r0 + i] += dden[i];
  }
  __syncthreads();
#pragma unroll
  for (int i = 0; i < 4; ++i) {
    const int r = r0 + i;
    const float invd = 1.f / den_s[r];
    float4 o = {acc[i][0] * invd, acc[i][1] * invd, acc[i][2] * invd,
                acc[i][3] * invd};
    *reinterpret_cast<float4*>(
        &out[((size_t)(b * L_ + c * T_ + r) * H_ + h) * D_ + c0]) = o;
  }
}

extern "C" void kernel_launch(void* const* d_in, const int* in_sizes, int n_in,
                              void* d_out, int out_size, void* d_ws,
                              size_t ws_size, hipStream_t stream) {
  const float* q = (const float*)d_in[0];
  const float* k = (const float*)d_in[1];
  const float* v = (const float*)d_in[2];
  const float* P = (const float*)d_in[3];
  float* out = (float*)d_out;

  // Workspace carve (~48.4 MB of floats)
  float* ws = (float*)d_ws;
  float* qp = ws;                                      // B*H*L*M
  float* kp = qp + (size_t)B_ * H_ * L_ * M_;          // B*H*L*M (dash -> k')
  float* kvp = kp + (size_t)B_ * H_ * L_ * M_;         // B*H*C*M*D
  float* ksp = kvp + (size_t)B_ * H_ * C_ * M_ * D_;   // B*H*C*M
  float* kdiag = ksp + (size_t)B_ * H_ * C_ * M_;      // B*H*L
  float* kmax = kdiag + (size_t)B_ * H_ * L_;          // B*H

  init_kmax_kernel<<<1, 64, 0, stream>>>(kmax);
  const int featGrid = B_ * H_ * (L_ / POS_);  // 2048
  feat_kernel<true><<<featGrid, 128, 0, stream>>>(q, P, qp, nullptr, nullptr);
  feat_kernel<false><<<featGrid, 128, 0, stream>>>(k, P, kp, kdiag, kmax);
  kexp_kernel<<<(B_ * H_ * L_ * M_ / 4) / 256, 256, 0, stream>>>(kp, kdiag, kmax);
  chunk_sum_kernel<<<B_ * H_ * C_, 256, 0, stream>>>(kp, v, kvp, ksp);
  prefix_kernel<<<B_ * H_ * 32, 256, 0, stream>>>(kvp, ksp);
  intra_kernel<<<B_ * H_ * C_, 256, 0, stream>>>(qp, kp, v, kvp, ksp, out);
}

// Round 2
// 128.225 us; speedup vs baseline: 3.0677x; 3.0677x over previous
//
#include <hip/hip_runtime.h>
#include <math.h>

// Problem constants (from setup_inputs): B=2, L=2048, H=8, D=64, M=128.
constexpr int B_ = 2, L_ = 2048, H_ = 8, D_ = 64, M_ = 128;
constexpr int T_ = 64;            // chunk length / feat l-tile
constexpr int C_ = L_ / T_;       // 32 chunks
constexpr float DN_ = 0.35355339059327373f;     // 64^-0.25
constexpr float RATIO_ = 0.08838834764831845f;  // 1/sqrt(128)
constexpr float EPSV_ = 1e-6f;

__device__ inline void atomicMaxFloat(float* addr, float val) {
  if (val >= 0.f) atomicMax((int*)addr, __float_as_int(val));
  else atomicMin((unsigned int*)addr, __float_as_uint(val));
}

__global__ void init_kmax_kernel(float* kmax) {
  if (threadIdx.x < B_ * H_) kmax[threadIdx.x] = -INFINITY;
}

// Feature map as LDS-tiled GEMM: dash[l, m] = (DN*x[l,:]) . P[m,:].
// Block: one (bh, 64-position tile). 256 threads; thread (lg,mg) owns
// rows l0..l0+3 (l0=4*lg) x cols m0..m0+7 (m0=8*mg). No per-thread P array
// (round-0 version spilled 273MB/dispatch of scratch traffic).
template <bool IS_Q>
__global__ __launch_bounds__(256) void feat_kernel(
    const float* __restrict__ x, const float* __restrict__ P,
    float* __restrict__ outp, float* __restrict__ diag_out,
    float* __restrict__ kmax) {
  __shared__ __align__(16) float x_s[T_][68];   // [l][d], pad 68 (17KB)
  __shared__ __align__(16) float p_s[D_][M_];   // P transposed [d][m] (32KB)
  __shared__ float red_s[4];
  const int bid = blockIdx.x;
  const int lt = bid % C_;
  const int bh = bid / C_;
  const int b = bh >> 3, h = bh & 7;
  const int tid = threadIdx.x;
  const int lg = tid >> 4, mg = tid & 15;
  const int l0 = lg * 4, m0 = mg * 8;

  // X tile (pre-scaled by DN_), coalesced float4
  for (int i4 = tid; i4 < T_ * 16; i4 += 256) {
    const int r = i4 >> 4, d0 = (i4 & 15) * 4;
    float4 t4 = *reinterpret_cast<const float4*>(
        &x[((size_t)(b * L_ + lt * T_ + r) * H_ + h) * D_ + d0]);
    t4.x *= DN_; t4.y *= DN_; t4.z *= DN_; t4.w *= DN_;
    *reinterpret_cast<float4*>(&x_s[r][d0]) = t4;
  }
  // P transposed into LDS (one-time scalar stores; hot loop reads are clean)
  for (int i = tid; i < M_ * D_ / 4; i += 256) {
    const int m = i >> 4, d0 = (i & 15) * 4;
    const float4 t4 = *reinterpret_cast<const float4*>(&P[m * D_ + d0]);
    p_s[d0][m] = t4.x; p_s[d0 + 1][m] = t4.y;
    p_s[d0 + 2][m] = t4.z; p_s[d0 + 3][m] = t4.w;
  }
  __syncthreads();

  float acc[4][8];
#pragma unroll
  for (int i = 0; i < 4; ++i)
#pragma unroll
    for (int j = 0; j < 8; ++j) acc[i][j] = 0.f;

#pragma unroll
  for (int d4 = 0; d4 < 16; ++d4) {
    float4 xv[4];
#pragma unroll
    for (int i = 0; i < 4; ++i)
      xv[i] = *reinterpret_cast<const float4*>(&x_s[l0 + i][d4 * 4]);
#pragma unroll
    for (int dd = 0; dd < 4; ++dd) {
      const int d = d4 * 4 + dd;
      const float4 pv0 = *reinterpret_cast<const float4*>(&p_s[d][m0]);
      const float4 pv1 = *reinterpret_cast<const float4*>(&p_s[d][m0 + 4]);
#pragma unroll
      for (int i = 0; i < 4; ++i) {
        const float xd = dd == 0 ? xv[i].x : dd == 1 ? xv[i].y
                       : dd == 2 ? xv[i].z : xv[i].w;
        acc[i][0] += xd * pv0.x; acc[i][1] += xd * pv0.y;
        acc[i][2] += xd * pv0.z; acc[i][3] += xd * pv0.w;
        acc[i][4] += xd * pv1.x; acc[i][5] += xd * pv1.y;
        acc[i][6] += xd * pv1.z; acc[i][7] += xd * pv1.w;
      }
    }
  }

  // diag[r] = 0.5*||x_r||^2 : per-thread partial over d=mg*4..+3, xor-reduce over mg
  float diag[4];
#pragma unroll
  for (int i = 0; i < 4; ++i) {
    const float4 xv = *reinterpret_cast<const float4*>(&x_s[l0 + i][mg * 4]);
    float s = xv.x * xv.x + xv.y * xv.y + xv.z * xv.z + xv.w * xv.w;
#pragma unroll
    for (int off = 1; off < 16; off <<= 1) s += __shfl_xor(s, off, 64);
    diag[i] = 0.5f * s;
  }

  float* outr = outp + ((size_t)bh * L_ + lt * T_) * M_;
  if (IS_Q) {
    // per-row stab = max over m (reduce over mg lanes)
#pragma unroll
    for (int i = 0; i < 4; ++i) {
      float mx = acc[i][0];
#pragma unroll
      for (int j = 1; j < 8; ++j) mx = fmaxf(mx, acc[i][j]);
#pragma unroll
      for (int off = 1; off < 16; off <<= 1) mx = fmaxf(mx, __shfl_xor(mx, off, 64));
      const float sub = diag[i] + mx;
      float4 o0, o1;
      o0.x = RATIO_ * (expf(acc[i][0] - sub) + EPSV_);
      o0.y = RATIO_ * (expf(acc[i][1] - sub) + EPSV_);
      o0.z = RATIO_ * (expf(acc[i][2] - sub) + EPSV_);
      o0.w = RATIO_ * (expf(acc[i][3] - sub) + EPSV_);
      o1.x = RATIO_ * (expf(acc[i][4] - sub) + EPSV_);
      o1.y = RATIO_ * (expf(acc[i][5] - sub) + EPSV_);
      o1.z = RATIO_ * (expf(acc[i][6] - sub) + EPSV_);
      o1.w = RATIO_ * (expf(acc[i][7] - sub) + EPSV_);
      *reinterpret_cast<float4*>(&outr[(l0 + i) * M_ + m0]) = o0;
      *reinterpret_cast<float4*>(&outr[(l0 + i) * M_ + m0 + 4]) = o1;
    }
  } else {
    // raw dash out + diag out + per-(b,h) running max
    float bm = -INFINITY;
#pragma unroll
    for (int i = 0; i < 4; ++i) {
      float4 o0 = {acc[i][0], acc[i][1], acc[i][2], acc[i][3]};
      float4 o1 = {acc[i][4], acc[i][5], acc[i][6], acc[i][7]};
      *reinterpret_cast<float4*>(&outr[(l0 + i) * M_ + m0]) = o0;
      *reinterpret_cast<float4*>(&outr[(l0 + i) * M_ + m0 + 4]) = o1;
#pragma unroll
      for (int j = 0; j < 8; ++j) bm = fmaxf(bm, acc[i][j]);
    }
    if (mg == 0) {
#pragma unroll
      for (int i = 0; i < 4; ++i)
        diag_out[(size_t)bh * L_ + lt * T_ + l0 + i] = diag[i];
    }
#pragma unroll
    for (int off = 1; off < 64; off <<= 1) bm = fmaxf(bm, __shfl_xor(bm, off, 64));
    if ((tid & 63) == 0) red_s[tid >> 6] = bm;
    __syncthreads();
    if (tid == 0)
      atomicMaxFloat(&kmax[bh],
                     fmaxf(fmaxf(red_s[0], red_s[1]), fmaxf(red_s[2], red_s[3])));
  }
}

// Elementwise: kp = ratio*(exp(dash - diag - kmax_bh) + eps), in place.
__global__ __launch_bounds__(256) void kexp_kernel(
    float* __restrict__ kp, const float* __restrict__ kdiag,
    const float* __restrict__ kmax) {
  const int idx4 = blockIdx.x * 256 + threadIdx.x;
  const int bh = idx4 >> 16;
  const int l = (idx4 >> 5) & (L_ - 1);
  float4 v = *reinterpret_cast<float4*>(kp + (size_t)idx4 * 4);
  const float sub = kdiag[(size_t)bh * L_ + l] + kmax[bh];
  v.x = RATIO_ * (expf(v.x - sub) + EPSV_);
  v.y = RATIO_ * (expf(v.y - sub) + EPSV_);
  v.z = RATIO_ * (expf(v.z - sub) + EPSV_);
  v.w = RATIO_ * (expf(v.w - sub) + EPSV_);
  *reinterpret_cast<float4*>(kp + (size_t)idx4 * 4) = v;
}

// Per-chunk local sums: KV_c[m][d] = sum_t kp[t][m]*v[t][d];  ks_c[m] = sum_t kp[t][m]
__global__ __launch_bounds__(256) void chunk_sum_kernel(
    const float* __restrict__ kp, const float* __restrict__ v,
    float* __restrict__ kvc, float* __restrict__ ksc) {
  __shared__ __align__(16) float kp_s[T_][M_];
  __shared__ __align__(16) float v_s[T_][D_];
  const int bid = blockIdx.x;
  const int c = bid % C_, bh = bid / C_;
  const int b = bh >> 3, h = bh & 7;
  const int tid = threadIdx.x;
  const float* kpt = kp + ((size_t)bh * L_ + c * T_) * M_;
  for (int i4 = tid; i4 < T_ * M_ / 4; i4 += 256)
    *reinterpret_cast<float4*>(&kp_s[0][0] + i4 * 4) =
        *reinterpret_cast<const float4*>(kpt + i4 * 4);
  for (int i4 = tid; i4 < T_ * D_ / 4; i4 += 256) {
    const int t = i4 >> 4, d0 = (i4 & 15) * 4;
    *reinterpret_cast<float4*>(&v_s[t][d0]) = *reinterpret_cast<const float4*>(
        &v[((size_t)(b * L_ + c * T_ + t) * H_ + h) * D_ + d0]);
  }
  __syncthreads();
  const int mg = tid >> 3;
  const int dg = tid & 7;
  float acc[4][8];
#pragma unroll
  for (int i = 0; i < 4; ++i)
#pragma unroll
    for (int j = 0; j < 8; ++j) acc[i][j] = 0.f;
  for (int t = 0; t < T_; ++t) {
    const float4 a4 = *reinterpret_cast<const float4*>(&kp_s[t][mg * 4]);
    const float4 v0 = *reinterpret_cast<const float4*>(&v_s[t][dg * 8]);
    const float4 v1 = *reinterpret_cast<const float4*>(&v_s[t][dg * 8 + 4]);
    const float a[4] = {a4.x, a4.y, a4.z, a4.w};
    const float vv[8] = {v0.x, v0.y, v0.z, v0.w, v1.x, v1.y, v1.z, v1.w};
#pragma unroll
    for (int i = 0; i < 4; ++i)
#pragma unroll
      for (int j = 0; j < 8; ++j) acc[i][j] += a[i] * vv[j];
  }
  float* outb = kvc + (size_t)(bh * C_ + c) * M_ * D_;
#pragma unroll
  for (int i = 0; i < 4; ++i) {
    float4 o0 = {acc[i][0], acc[i][1], acc[i][2], acc[i][3]};
    float4 o1 = {acc[i][4], acc[i][5], acc[i][6], acc[i][7]};
    *reinterpret_cast<float4*>(&outb[(mg * 4 + i) * D_ + dg * 8]) = o0;
    *reinterpret_cast<float4*>(&outb[(mg * 4 + i) * D_ + dg * 8 + 4]) = o1;
  }
  if (tid < M_) {
    float s = 0.f;
    for (int t = 0; t < T_; ++t) s += kp_s[t][tid];
    ksc[(size_t)(bh * C_ + c) * M_ + tid] = s;
  }
}

// Exclusive prefix across chunks, register-staged (independent loads pipeline).
__global__ __launch_bounds__(256) void prefix_kernel(float* __restrict__ kvc,
                                                     float* __restrict__ ksc) {
  const int bid = blockIdx.x;  // B*H*32
  const int ej = bid & 31, bh = bid >> 5;
  const int e = ej * 256 + threadIdx.x;
  float vals[C_];
#pragma unroll
  for (int c = 0; c < C_; ++c)
    vals[c] = kvc[(size_t)(bh * C_ + c) * (M_ * D_) + e];
  float run = 0.f;
#pragma unroll
  for (int c = 0; c < C_; ++c) { const float t = vals[c]; vals[c] = run; run += t; }
#pragma unroll
  for (int c = 0; c < C_; ++c)
    kvc[(size_t)(bh * C_ + c) * (M_ * D_) + e] = vals[c];
  if (ej == 0 && threadIdx.x < M_) {
    const int m = threadIdx.x;
    float ks[C_];
#pragma unroll
    for (int c = 0; c < C_; ++c) ks[c] = ksc[(size_t)(bh * C_ + c) * M_ + m];
    float rs = 0.f;
#pragma unroll
    for (int c = 0; c < C_; ++c) { const float t = ks[c]; ks[c] = rs; rs += t; }
#pragma unroll
    for (int c = 0; c < C_; ++c) ksc[(size_t)(bh * C_ + c) * M_ + m] = ks[c];
  }
}

// Intra-chunk: S = Qp Kp^T (tril-masked), num = S_m V + Qp KVprefix,
// den = rowsum(S_m) + Qp . ksprefix;  out = num/den.
__global__ __launch_bounds__(256) void intra_kernel(
    const float* __restrict__ qp, const float* __restrict__ kp,
    const float* __restrict__ v, const float* __restrict__ kvp,
    const float* __restrict__ ksp, float* __restrict__ out) {
  __shared__ __align__(16) float smem[3 * T_ * 68 + M_ + T_];
  float* bufA = smem;
  float* bufB = smem + T_ * 68;
  float* S_s = smem + 2 * T_ * 68;
  float* ksp_s = smem + 3 * T_ * 68;
  float* den_s = ksp_s + M_;

  const int bid = blockIdx.x;
  const int c = bid % C_, bh = bid / C_;
  const int b = bh >> 3, h = bh & 7;
  const int tid = threadIdx.x;
  const int tr = tid >> 4, tc = tid & 15;
  const int r0 = tr * 4, c0 = tc * 4;

  const float* qpt = qp + ((size_t)bh * L_ + c * T_) * M_;
  const float* kpt = kp + ((size_t)bh * L_ + c * T_) * M_;

  float acc[4][4];
#pragma unroll
  for (int i = 0; i < 4; ++i)
#pragma unroll
    for (int j = 0; j < 4; ++j) acc[i][j] = 0.f;

  for (int ks = 0; ks < 2; ++ks) {
    if (ks) __syncthreads();
    for (int i4 = tid; i4 < T_ * 16; i4 += 256) {
      const int t = i4 >> 4, d0 = (i4 & 15) * 4;
      *reinterpret_cast<float4*>(&bufA[t * 68 + d0]) =
          *reinterpret_cast<const float4*>(&qpt[t * M_ + ks * 64 + d0]);
      *reinterpret_cast<float4*>(&bufB[t * 68 + d0]) =
          *reinterpret_cast<const float4*>(&kpt[t * M_ + ks * 64 + d0]);
    }
    __syncthreads();
    for (int k4 = 0; k4 < 16; ++k4) {
      float4 qv[4], kv[4];
#pragma unroll
      for (int i = 0; i < 4; ++i)
        qv[i] = *reinterpret_cast<const float4*>(&bufA[(r0 + i) * 68 + k4 * 4]);
#pragma unroll
      for (int j = 0; j < 4; ++j)
        kv[j] = *reinterpret_cast<const float4*>(&bufB[(c0 + j) * 68 + k4 * 4]);
#pragma unroll
      for (int i = 0; i < 4; ++i)
#pragma unroll
        for (int j = 0; j < 4; ++j)
          acc[i][j] += qv[i].x * kv[j].x + qv[i].y * kv[j].y +
                       qv[i].z * kv[j].z + qv[i].w * kv[j].w;
    }
  }
  float dpart[4];
#pragma unroll
  for (int i = 0; i < 4; ++i) {
    const int r = r0 + i;
    float s[4];
#pragma unroll
    for (int j = 0; j < 4; ++j) s[j] = (c0 + j <= r) ? acc[i][j] : 0.f;
    float4 sv = {s[0], s[1], s[2], s[3]};
    *reinterpret_cast<float4*>(&S_s[r * 68 + c0]) = sv;
    dpart[i] = s[0] + s[1] + s[2] + s[3];
  }
#pragma unroll
  for (int off = 1; off < 16; off <<= 1)
#pragma unroll
    for (int i = 0; i < 4; ++i) dpart[i] += __shfl_xor(dpart[i], off, 64);
  if (tc == 0) {
#pragma unroll
    for (int i = 0; i < 4; ++i) den_s[r0 + i] = dpart[i];
  }
  __syncthreads();
  for (int i4 = tid; i4 < T_ * 16; i4 += 256) {
    const int t = i4 >> 4, d0 = (i4 & 15) * 4;
    *reinterpret_cast<float4*>(&bufA[t * 68 + d0]) =
        *reinterpret_cast<const float4*>(
            &v[((size_t)(b * L_ + c * T_ + t) * H_ + h) * D_ + d0]);
  }
  if (tid < M_) ksp_s[tid] = ksp[(size_t)(bh * C_ + c) * M_ + tid];
  __syncthreads();
#pragma unroll
  for (int i = 0; i < 4; ++i)
#pragma unroll
    for (int j = 0; j < 4; ++j) acc[i][j] = 0.f;
  for (int k4 = 0; k4 < 16; ++k4) {
    float4 sv[4];
#pragma unroll
    for (int i = 0; i < 4; ++i)
      sv[i] = *reinterpret_cast<const float4*>(&S_s[(r0 + i) * 68 + k4 * 4]);
#pragma unroll
    for (int j = 0; j < 4; ++j) {
      const int tp = k4 * 4 + j;
      const float4 vv = *reinterpret_cast<const float4*>(&bufA[tp * 68 + c0]);
#pragma unroll
      for (int i = 0; i < 4; ++i) {
        const float sj = j == 0 ? sv[i].x : j == 1 ? sv[i].y
                       : j == 2 ? sv[i].z : sv[i].w;
        acc[i][0] += sj * vv.x; acc[i][1] += sj * vv.y;
        acc[i][2] += sj * vv.z; acc[i][3] += sj * vv.w;
      }
    }
  }
  float dden[4] = {0.f, 0.f, 0.f, 0.f};
  const float* kvpc = kvp + (size_t)(bh * C_ + c) * M_ * D_;
  for (int ks = 0; ks < 2; ++ks) {
    __syncthreads();
    for (int i4 = tid; i4 < T_ * 16; i4 += 256) {
      const int t = i4 >> 4, d0 = (i4 & 15) * 4;
      *reinterpret_cast<float4*>(&bufA[t * 68 + d0]) =
          *reinterpret_cast<const float4*>(&qpt[t * M_ + ks * 64 + d0]);
      *reinterpret_cast<float4*>(&bufB[t * 68 + d0]) =
          *reinterpret_cast<const float4*>(&kvpc[(ks * 64 + t) * D_ + d0]);
    }
    __syncthreads();
    for (int m4 = 0; m4 < 16; ++m4) {
      float4 qv[4];
#pragma unroll
      for (int i = 0; i < 4; ++i)
        qv[i] = *reinterpret_cast<const float4*>(&bufA[(r0 + i) * 68 + m4 * 4]);
#pragma unroll
      for (int j = 0; j < 4; ++j) {
        const int mrow = m4 * 4 + j;
        const float4 kvv = *reinterpret_cast<const float4*>(&bufB[mrow * 68 + c0]);
        const float km = ksp_s[ks * 64 + mrow];
#pragma unroll
        for (int i = 0; i < 4; ++i) {
          const float qj = j == 0 ? qv[i].x : j == 1 ? qv[i].y
                        : j == 2 ? qv[i].z : qv[i].w;
          dden[i] += qj * km;
          acc[i][0] += qj * kvv.x; acc[i][1] += qj * kvv.y;
          acc[i][2] += qj * kvv.z; acc[i][3] += qj * kvv.w;
        }
      }
    }
  }
  if (tc == 0) {
#pragma unroll
    for (int i = 0; i < 4; ++i) den_s[r0 + i] += dden[i];
  }
  __syncthreads();
#pragma unroll
  for (int i = 0; i < 4; ++i) {
    const int r = r0 + i;
    const float invd = 1.f / den_s[r];
    float4 o = {acc[i][0] * invd, acc[i][1] * invd, acc[i][2] * invd,
                acc[i][3] * invd};
    *reinterpret_cast<float4*>(
        &out[((size_t)(b * L_ + c * T_ + r) * H_ + h) * D_ + c0]) = o;
  }
}

extern "C" void kernel_launch(void* const* d_in, const int* in_sizes, int n_in,
                              void* d_out, int out_size, void* d_ws,
                              size_t ws_size, hipStream_t stream) {
  const float* q = (const float*)d_in[0];
  const float* k = (const float*)d_in[1];
  const float* v = (const float*)d_in[2];
  const float* P = (const float*)d_in[3];
  float* out = (float*)d_out;

  float* ws = (float*)d_ws;
  float* qp = ws;                                      // B*H*L*M
  float* kp = qp + (size_t)B_ * H_ * L_ * M_;          // B*H*L*M (dash -> k')
  float* kvp = kp + (size_t)B_ * H_ * L_ * M_;         // B*H*C*M*D
  float* ksp = kvp + (size_t)B_ * H_ * C_ * M_ * D_;   // B*H*C*M
  float* kdiag = ksp + (size_t)B_ * H_ * C_ * M_;      // B*H*L
  float* kmax = kdiag + (size_t)B_ * H_ * L_;          // B*H

  init_kmax_kernel<<<1, 64, 0, stream>>>(kmax);
  const int featGrid = B_ * H_ * C_;  // 512
  feat_kernel<true><<<featGrid, 256, 0, stream>>>(q, P, qp, nullptr, nullptr);
  feat_kernel<false><<<featGrid, 256, 0, stream>>>(k, P, kp, kdiag, kmax);
  kexp_kernel<<<(B_ * H_ * L_ * M_ / 4) / 256, 256, 0, stream>>>(kp, kdiag, kmax);
  chunk_sum_kernel<<<B_ * H_ * C_, 256, 0, stream>>>(kp, v, kvp, ksp);
  prefix_kernel<<<B_ * H_ * 32, 256, 0, stream>>>(kvp, ksp);
  intra_kernel<<<B_ * H_ * C_, 256, 0, stream>>>(qp, kp, v, kvp, ksp, out);
}

// Round 3
// 79.346 us; speedup vs baseline: 4.9574x; 1.6160x over previous
//
#include <hip/hip_runtime.h>
#include <math.h>

typedef __attribute__((ext_vector_type(8))) short short8;
typedef __attribute__((ext_vector_type(4))) float f32x4;
typedef __attribute__((ext_vector_type(4))) unsigned short u16x4;

// Problem constants: B=2, L=2048, H=8, D=64, M=128.
constexpr int B_ = 2, L_ = 2048, H_ = 8, D_ = 64, M_ = 128;
constexpr int T_ = 64;            // chunk length
constexpr int C_ = L_ / T_;       // 32 chunks
constexpr float DN_ = 0.35355339059327373f;     // 64^-0.25
constexpr float RATIO_ = 0.08838834764831845f;  // 1/sqrt(128)
constexpr float EPSV_ = 1e-6f;

__device__ inline unsigned short f2bf(float x) {  // RNE float->bf16
  const unsigned u = __float_as_uint(x);
  return (unsigned short)((u + 0x7fffu + ((u >> 16) & 1u)) >> 16);
}
__device__ inline float bf2f(unsigned short h) {
  return __uint_as_float(((unsigned)h) << 16);
}

__device__ inline void atomicMaxFloat(float* addr, float val) {
  if (val >= 0.f) atomicMax((int*)addr, __float_as_int(val));
  else atomicMin((unsigned int*)addr, __float_as_uint(val));
}

__global__ void init_kmax_kernel(float* kmax) {
  if (threadIdx.x < B_ * H_) kmax[threadIdx.x] = -INFINITY;
}

// Q feature map: LDS-tiled fp32 GEMM, writes bf16 q' directly.
__global__ __launch_bounds__(256) void feat_q_kernel(
    const float* __restrict__ x, const float* __restrict__ P,
    unsigned short* __restrict__ outp) {
  __shared__ __align__(16) float x_s[T_][68];
  __shared__ __align__(16) float p_s[D_][M_];
  const int bid = blockIdx.x;
  const int lt = bid % C_;
  const int bh = bid / C_;
  const int b = bh >> 3, h = bh & 7;
  const int tid = threadIdx.x;
  const int lg = tid >> 4, mg = tid & 15;
  const int l0 = lg * 4, m0 = mg * 8;

  for (int i4 = tid; i4 < T_ * 16; i4 += 256) {
    const int r = i4 >> 4, d0 = (i4 & 15) * 4;
    float4 t4 = *reinterpret_cast<const float4*>(
        &x[((size_t)(b * L_ + lt * T_ + r) * H_ + h) * D_ + d0]);
    t4.x *= DN_; t4.y *= DN_; t4.z *= DN_; t4.w *= DN_;
    *reinterpret_cast<float4*>(&x_s[r][d0]) = t4;
  }
  for (int i = tid; i < M_ * D_ / 4; i += 256) {
    const int m = i >> 4, d0 = (i & 15) * 4;
    const float4 t4 = *reinterpret_cast<const float4*>(&P[m * D_ + d0]);
    p_s[d0][m] = t4.x; p_s[d0 + 1][m] = t4.y;
    p_s[d0 + 2][m] = t4.z; p_s[d0 + 3][m] = t4.w;
  }
  __syncthreads();

  float acc[4][8];
#pragma unroll
  for (int i = 0; i < 4; ++i)
#pragma unroll
    for (int j = 0; j < 8; ++j) acc[i][j] = 0.f;

#pragma unroll
  for (int d4 = 0; d4 < 16; ++d4) {
    float4 xv[4];
#pragma unroll
    for (int i = 0; i < 4; ++i)
      xv[i] = *reinterpret_cast<const float4*>(&x_s[l0 + i][d4 * 4]);
#pragma unroll
    for (int dd = 0; dd < 4; ++dd) {
      const int d = d4 * 4 + dd;
      const float4 pv0 = *reinterpret_cast<const float4*>(&p_s[d][m0]);
      const float4 pv1 = *reinterpret_cast<const float4*>(&p_s[d][m0 + 4]);
#pragma unroll
      for (int i = 0; i < 4; ++i) {
        const float xd = dd == 0 ? xv[i].x : dd == 1 ? xv[i].y
                       : dd == 2 ? xv[i].z : xv[i].w;
        acc[i][0] += xd * pv0.x; acc[i][1] += xd * pv0.y;
        acc[i][2] += xd * pv0.z; acc[i][3] += xd * pv0.w;
        acc[i][4] += xd * pv1.x; acc[i][5] += xd * pv1.y;
        acc[i][6] += xd * pv1.z; acc[i][7] += xd * pv1.w;
      }
    }
  }
  float diag[4];
#pragma unroll
  for (int i = 0; i < 4; ++i) {
    const float4 xv = *reinterpret_cast<const float4*>(&x_s[l0 + i][mg * 4]);
    float s = xv.x * xv.x + xv.y * xv.y + xv.z * xv.z + xv.w * xv.w;
#pragma unroll
    for (int off = 1; off < 16; off <<= 1) s += __shfl_xor(s, off, 64);
    diag[i] = 0.5f * s;
  }
  unsigned short* outr = outp + ((size_t)bh * L_ + lt * T_) * M_;
#pragma unroll
  for (int i = 0; i < 4; ++i) {
    float mx = acc[i][0];
#pragma unroll
    for (int j = 1; j < 8; ++j) mx = fmaxf(mx, acc[i][j]);
#pragma unroll
    for (int off = 1; off < 16; off <<= 1) mx = fmaxf(mx, __shfl_xor(mx, off, 64));
    const float sub = diag[i] + mx;
    short8 o;
#pragma unroll
    for (int j = 0; j < 8; ++j)
      o[j] = (short)f2bf(RATIO_ * (expf(acc[i][j] - sub) + EPSV_));
    *reinterpret_cast<short8*>(&outr[(l0 + i) * M_ + m0]) = o;
  }
}

// K feature map: raw dash (fp32) + diag + per-(b,h) running max.
__global__ __launch_bounds__(256) void feat_k_kernel(
    const float* __restrict__ x, const float* __restrict__ P,
    float* __restrict__ dash, float* __restrict__ diag_out,
    float* __restrict__ kmax) {
  __shared__ __align__(16) float x_s[T_][68];
  __shared__ __align__(16) float p_s[D_][M_];
  __shared__ float red_s[4];
  const int bid = blockIdx.x;
  const int lt = bid % C_;
  const int bh = bid / C_;
  const int b = bh >> 3, h = bh & 7;
  const int tid = threadIdx.x;
  const int lg = tid >> 4, mg = tid & 15;
  const int l0 = lg * 4, m0 = mg * 8;

  for (int i4 = tid; i4 < T_ * 16; i4 += 256) {
    const int r = i4 >> 4, d0 = (i4 & 15) * 4;
    float4 t4 = *reinterpret_cast<const float4*>(
        &x[((size_t)(b * L_ + lt * T_ + r) * H_ + h) * D_ + d0]);
    t4.x *= DN_; t4.y *= DN_; t4.z *= DN_; t4.w *= DN_;
    *reinterpret_cast<float4*>(&x_s[r][d0]) = t4;
  }
  for (int i = tid; i < M_ * D_ / 4; i += 256) {
    const int m = i >> 4, d0 = (i & 15) * 4;
    const float4 t4 = *reinterpret_cast<const float4*>(&P[m * D_ + d0]);
    p_s[d0][m] = t4.x; p_s[d0 + 1][m] = t4.y;
    p_s[d0 + 2][m] = t4.z; p_s[d0 + 3][m] = t4.w;
  }
  __syncthreads();

  float acc[4][8];
#pragma unroll
  for (int i = 0; i < 4; ++i)
#pragma unroll
    for (int j = 0; j < 8; ++j) acc[i][j] = 0.f;

#pragma unroll
  for (int d4 = 0; d4 < 16; ++d4) {
    float4 xv[4];
#pragma unroll
    for (int i = 0; i < 4; ++i)
      xv[i] = *reinterpret_cast<const float4*>(&x_s[l0 + i][d4 * 4]);
#pragma unroll
    for (int dd = 0; dd < 4; ++dd) {
      const int d = d4 * 4 + dd;
      const float4 pv0 = *reinterpret_cast<const float4*>(&p_s[d][m0]);
      const float4 pv1 = *reinterpret_cast<const float4*>(&p_s[d][m0 + 4]);
#pragma unroll
      for (int i = 0; i < 4; ++i) {
        const float xd = dd == 0 ? xv[i].x : dd == 1 ? xv[i].y
                       : dd == 2 ? xv[i].z : xv[i].w;
        acc[i][0] += xd * pv0.x; acc[i][1] += xd * pv0.y;
        acc[i][2] += xd * pv0.z; acc[i][3] += xd * pv0.w;
        acc[i][4] += xd * pv1.x; acc[i][5] += xd * pv1.y;
        acc[i][6] += xd * pv1.z; acc[i][7] += xd * pv1.w;
      }
    }
  }
  float diag[4];
#pragma unroll
  for (int i = 0; i < 4; ++i) {
    const float4 xv = *reinterpret_cast<const float4*>(&x_s[l0 + i][mg * 4]);
    float s = xv.x * xv.x + xv.y * xv.y + xv.z * xv.z + xv.w * xv.w;
#pragma unroll
    for (int off = 1; off < 16; off <<= 1) s += __shfl_xor(s, off, 64);
    diag[i] = 0.5f * s;
  }
  float* outr = dash + ((size_t)bh * L_ + lt * T_) * M_;
  float bm = -INFINITY;
#pragma unroll
  for (int i = 0; i < 4; ++i) {
    float4 o0 = {acc[i][0], acc[i][1], acc[i][2], acc[i][3]};
    float4 o1 = {acc[i][4], acc[i][5], acc[i][6], acc[i][7]};
    *reinterpret_cast<float4*>(&outr[(l0 + i) * M_ + m0]) = o0;
    *reinterpret_cast<float4*>(&outr[(l0 + i) * M_ + m0 + 4]) = o1;
#pragma unroll
    for (int j = 0; j < 8; ++j) bm = fmaxf(bm, acc[i][j]);
  }
  if (mg == 0) {
#pragma unroll
    for (int i = 0; i < 4; ++i)
      diag_out[(size_t)bh * L_ + lt * T_ + l0 + i] = diag[i];
  }
#pragma unroll
  for (int off = 1; off < 64; off <<= 1) bm = fmaxf(bm, __shfl_xor(bm, off, 64));
  if ((tid & 63) == 0) red_s[tid >> 6] = bm;
  __syncthreads();
  if (tid == 0)
    atomicMaxFloat(&kmax[bh],
                   fmaxf(fmaxf(red_s[0], red_s[1]), fmaxf(red_s[2], red_s[3])));
}

// Fused: k' = ratio*(exp(dash-diag-kmax)+eps)  (writes bf16 kp16),
// local chunk sums KV^T[d][m] (bf16) and ks[m] (fp32).
__global__ __launch_bounds__(256) void chunk_sum_kernel(
    const float* __restrict__ dash, const float* __restrict__ kdiag,
    const float* __restrict__ kmax, const float* __restrict__ v,
    unsigned short* __restrict__ kp16, unsigned short* __restrict__ kvc16,
    float* __restrict__ ksc) {
  __shared__ __align__(16) float kp_s[T_][M_];  // 32KB
  __shared__ __align__(16) float v_s[T_][D_];   // 16KB
  const int bid = blockIdx.x;
  const int c = bid % C_, bh = bid / C_;
  const int b = bh >> 3, h = bh & 7;
  const int tid = threadIdx.x;
  const float kmx = kmax[bh];
  const float* dsh = dash + ((size_t)bh * L_ + c * T_) * M_;
  unsigned short* kpo = kp16 + ((size_t)bh * L_ + c * T_) * M_;

  for (int i4 = tid; i4 < T_ * 32; i4 += 256) {
    const int t = i4 >> 5, m0 = (i4 & 31) * 4;
    const f32x4 dv = *reinterpret_cast<const f32x4*>(&dsh[t * M_ + m0]);
    const float sub = kdiag[(size_t)bh * L_ + c * T_ + t] + kmx;
    f32x4 kv;
#pragma unroll
    for (int j = 0; j < 4; ++j) kv[j] = RATIO_ * (expf(dv[j] - sub) + EPSV_);
    *reinterpret_cast<f32x4*>(&kp_s[t][m0]) = kv;
    u16x4 o;
#pragma unroll
    for (int j = 0; j < 4; ++j) o[j] = f2bf(kv[j]);
    *reinterpret_cast<u16x4*>(&kpo[t * M_ + m0]) = o;
  }
  for (int i4 = tid; i4 < T_ * 16; i4 += 256) {
    const int t = i4 >> 4, d0 = (i4 & 15) * 4;
    *reinterpret_cast<f32x4*>(&v_s[t][d0]) = *reinterpret_cast<const f32x4*>(
        &v[((size_t)(b * L_ + c * T_ + t) * H_ + h) * D_ + d0]);
  }
  __syncthreads();

  const int mgr = tid & 15, dgr = tid >> 4;  // m0=mgr*4 (+64), d0=dgr*4
  const int m0 = mgr * 4, d0 = dgr * 4;
  float acc[4][8];
#pragma unroll
  for (int i = 0; i < 4; ++i)
#pragma unroll
    for (int j = 0; j < 8; ++j) acc[i][j] = 0.f;
  for (int t = 0; t < T_; ++t) {
    const f32x4 vv = *reinterpret_cast<const f32x4*>(&v_s[t][d0]);
    const f32x4 a0 = *reinterpret_cast<const f32x4*>(&kp_s[t][m0]);
    const f32x4 a1 = *reinterpret_cast<const f32x4*>(&kp_s[t][m0 + 64]);
#pragma unroll
    for (int i = 0; i < 4; ++i)
#pragma unroll
      for (int j = 0; j < 4; ++j) {
        acc[i][j] += vv[i] * a0[j];
        acc[i][j + 4] += vv[i] * a1[j];
      }
  }
  unsigned short* ob = kvc16 + (size_t)(bh * C_ + c) * (M_ * D_);
#pragma unroll
  for (int i = 0; i < 4; ++i) {
    u16x4 p0, p1;
#pragma unroll
    for (int j = 0; j < 4; ++j) { p0[j] = f2bf(acc[i][j]); p1[j] = f2bf(acc[i][j + 4]); }
    *reinterpret_cast<u16x4*>(&ob[(d0 + i) * M_ + m0]) = p0;
    *reinterpret_cast<u16x4*>(&ob[(d0 + i) * M_ + m0 + 64]) = p1;
  }
  if (tid < M_) {
    float s = 0.f;
    for (int t = 0; t < T_; ++t) s += kp_s[t][tid];
    ksc[(size_t)(bh * C_ + c) * M_ + tid] = s;
  }
}

// Exclusive prefix across chunks: kvc16 (bf16) -> fp32 scan -> kvp16 (bf16);
// ksc fp32 scan in place.
__global__ __launch_bounds__(256) void prefix_kernel(
    const unsigned short* __restrict__ kvc16,
    unsigned short* __restrict__ kvp16, float* __restrict__ ksc) {
  const int bid = blockIdx.x;  // B*H*32
  const int ej = bid & 31, bh = bid >> 5;
  const int e = ej * 256 + threadIdx.x;  // element of [D][M]
  float vals[C_];
#pragma unroll
  for (int c = 0; c < C_; ++c)
    vals[c] = bf2f(kvc16[(size_t)(bh * C_ + c) * (M_ * D_) + e]);
  float run = 0.f;
#pragma unroll
  for (int c = 0; c < C_; ++c) { const float t = vals[c]; vals[c] = run; run += t; }
#pragma unroll
  for (int c = 0; c < C_; ++c)
    kvp16[(size_t)(bh * C_ + c) * (M_ * D_) + e] = f2bf(vals[c]);
  if (ej == 0 && threadIdx.x < M_) {
    const int m = threadIdx.x;
    float ks[C_];
#pragma unroll
    for (int c = 0; c < C_; ++c) ks[c] = ksc[(size_t)(bh * C_ + c) * M_ + m];
    float rs = 0.f;
#pragma unroll
    for (int c = 0; c < C_; ++c) { const float t = ks[c]; ks[c] = rs; rs += t; }
#pragma unroll
    for (int c = 0; c < C_; ++c) ksc[(size_t)(bh * C_ + c) * M_ + m] = ks[c];
  }
}

// Intra-chunk, MFMA bf16. 4 waves; wave w owns rows rblk=(w>>1)*32 and
// S-cols / out-d cols blk (w&1)*32. All GEMMs in NT form (contraction on the
// fast axis of both operands) so A and B fragments are identical contiguous
// 16B LDS reads: lane l reads row (l&15), cols (l>>4)*8 of a row-major tile.
__global__ __launch_bounds__(256) void intra_kernel(
    const unsigned short* __restrict__ qp16,
    const unsigned short* __restrict__ kp16, const float* __restrict__ v,
    const unsigned short* __restrict__ kvp16, const float* __restrict__ ksp,
    float* __restrict__ out) {
  __shared__ __align__(16) unsigned short qp_s[T_][136];   // [t][m] +8 pad
  __shared__ __align__(16) unsigned short kp_s[T_][136];   // [t'][m]
  __shared__ __align__(16) unsigned short kvp_s[D_][136];  // [d][m]
  __shared__ __align__(16) unsigned short S_s[T_][72];     // [t][t'] +8 pad
  __shared__ __align__(16) unsigned short vt_s[D_][72];    // [d][t']
  __shared__ float ksp_s[M_];
  __shared__ float denp_s[4][T_];
  __shared__ float den_s[T_];

  const int bid = blockIdx.x;
  const int c = bid % C_, bh = bid / C_;
  const int b = bh >> 3, h = bh & 7;
  const int tid = threadIdx.x;
  const int w = tid >> 6, lane = tid & 63;
  const int l15 = lane & 15, l16 = lane >> 4;

  const unsigned short* qpt = qp16 + ((size_t)bh * L_ + c * T_) * M_;
  const unsigned short* kpt = kp16 + ((size_t)bh * L_ + c * T_) * M_;
  const unsigned short* kvt = kvp16 + (size_t)(bh * C_ + c) * (M_ * D_);

  for (int i8 = tid; i8 < T_ * 16; i8 += 256) {
    const int r = i8 >> 4, m0 = (i8 & 15) * 8;
    *reinterpret_cast<short8*>(&qp_s[r][m0]) =
        *reinterpret_cast<const short8*>(&qpt[r * M_ + m0]);
    *reinterpret_cast<short8*>(&kp_s[r][m0]) =
        *reinterpret_cast<const short8*>(&kpt[r * M_ + m0]);
    *reinterpret_cast<short8*>(&kvp_s[r][m0]) =
        *reinterpret_cast<const short8*>(&kvt[r * M_ + m0]);
  }
  // V^T tile: lane-contiguous t -> conflict-free ds writes
  for (int i = tid; i < T_ * D_; i += 256) {
    const int t = i & 63, d = i >> 6;
    vt_s[d][t] = f2bf(v[((size_t)(b * L_ + c * T_ + t) * H_ + h) * D_ + d]);
  }
  if (tid < M_) ksp_s[tid] = ksp[(size_t)(bh * C_ + c) * M_ + tid];
  __syncthreads();

  const int rblk = (w >> 1) * 32, cblk = (w & 1) * 32;
  f32x4 Sacc[2][2];
#pragma unroll
  for (int i = 0; i < 2; ++i)
#pragma unroll
    for (int j = 0; j < 2; ++j) Sacc[i][j] = {0.f, 0.f, 0.f, 0.f};

#pragma unroll
  for (int kk = 0; kk < 4; ++kk) {
    short8 af[2], bf[2];
#pragma unroll
    for (int ti = 0; ti < 2; ++ti)
      af[ti] = *reinterpret_cast<const short8*>(
          &qp_s[rblk + ti * 16 + l15][kk * 32 + l16 * 8]);
#pragma unroll
    for (int tj = 0; tj < 2; ++tj)
      bf[tj] = *reinterpret_cast<const short8*>(
          &kp_s[cblk + tj * 16 + l15][kk * 32 + l16 * 8]);
#pragma unroll
    for (int ti = 0; ti < 2; ++ti)
#pragma unroll
      for (int tj = 0; tj < 2; ++tj)
        Sacc[ti][tj] = __builtin_amdgcn_mfma_f32_16x16x32_bf16(
            af[ti], bf[tj], Sacc[ti][tj], 0, 0, 0);
  }
  // causal mask (col<=row) + bf16 -> S_s
#pragma unroll
  for (int ti = 0; ti < 2; ++ti)
#pragma unroll
    for (int tj = 0; tj < 2; ++tj)
#pragma unroll
      for (int j = 0; j < 4; ++j) {
        const int row = rblk + ti * 16 + l16 * 4 + j;
        const int col = cblk + tj * 16 + l15;
        const float sv = (col <= row) ? Sacc[ti][tj][j] : 0.f;
        S_s[row][col] = f2bf(sv);
      }
  __syncthreads();

  // den partials: w0/w1 = S row-sum halves, w2/w3 = qp . ksp halves
  {
    const int t = lane;
    float p = 0.f;
    if (w == 0) {
      for (int tp = 0; tp < 32; ++tp) p += bf2f(S_s[t][tp]);
    } else if (w == 1) {
      for (int tp = 32; tp < 64; ++tp) p += bf2f(S_s[t][tp]);
    } else if (w == 2) {
      for (int m = 0; m < 64; ++m) p += bf2f(qp_s[t][m]) * ksp_s[m];
    } else {
      for (int m = 64; m < 128; ++m) p += bf2f(qp_s[t][m]) * ksp_s[m];
    }
    denp_s[w][t] = p;
  }
  __syncthreads();
  if (tid < T_)
    den_s[tid] = denp_s[0][tid] + denp_s[1][tid] + denp_s[2][tid] + denp_s[3][tid];
  __syncthreads();

  // num = S@V^T' + Qp@KVp^T'  (both NT), accumulate together
  const int dblk = (w & 1) * 32;
  f32x4 Nacc[2][2];
#pragma unroll
  for (int i = 0; i < 2; ++i)
#pragma unroll
    for (int j = 0; j < 2; ++j) Nacc[i][j] = {0.f, 0.f, 0.f, 0.f};

#pragma unroll
  for (int kk = 0; kk < 2; ++kk) {  // over t' (K=64)
    short8 af[2], bf[2];
#pragma unroll
    for (int ti = 0; ti < 2; ++ti)
      af[ti] = *reinterpret_cast<const short8*>(
          &S_s[rblk + ti * 16 + l15][kk * 32 + l16 * 8]);
#pragma unroll
    for (int tj = 0; tj < 2; ++tj)
      bf[tj] = *reinterpret_cast<const short8*>(
          &vt_s[dblk + tj * 16 + l15][kk * 32 + l16 * 8]);
#pragma unroll
    for (int ti = 0; ti < 2; ++ti)
#pragma unroll
      for (int tj = 0; tj < 2; ++tj)
        Nacc[ti][tj] = __builtin_amdgcn_mfma_f32_16x16x32_bf16(
            af[ti], bf[tj], Nacc[ti][tj], 0, 0, 0);
  }
#pragma unroll
  for (int kk = 0; kk < 4; ++kk) {  // over m (K=128)
    short8 af[2], bf[2];
#pragma unroll
    for (int ti = 0; ti < 2; ++ti)
      af[ti] = *reinterpret_cast<const short8*>(
          &qp_s[rblk + ti * 16 + l15][kk * 32 + l16 * 8]);
#pragma unroll
    for (int tj = 0; tj < 2; ++tj)
      bf[tj] = *reinterpret_cast<const short8*>(
          &kvp_s[dblk + tj * 16 + l15][kk * 32 + l16 * 8]);
#pragma unroll
    for (int ti = 0; ti < 2; ++ti)
#pragma unroll
      for (int tj = 0; tj < 2; ++tj)
        Nacc[ti][tj] = __builtin_amdgcn_mfma_f32_16x16x32_bf16(
            af[ti], bf[tj], Nacc[ti][tj], 0, 0, 0);
  }

#pragma unroll
  for (int ti = 0; ti < 2; ++ti)
#pragma unroll
    for (int j = 0; j < 4; ++j) {
      const int row = rblk + ti * 16 + l16 * 4 + j;
      const float r = 1.f / den_s[row];
      float* orow = out + ((size_t)(b * L_ + c * T_ + row) * H_ + h) * D_;
#pragma unroll
      for (int tj = 0; tj < 2; ++tj) {
        const int col = dblk + tj * 16 + l15;
        orow[col] = Nacc[ti][tj][j] * r;
      }
    }
}

extern "C" void kernel_launch(void* const* d_in, const int* in_sizes, int n_in,
                              void* d_out, int out_size, void* d_ws,
                              size_t ws_size, hipStream_t stream) {
  const float* q = (const float*)d_in[0];
  const float* k = (const float*)d_in[1];
  const float* v = (const float*)d_in[2];
  const float* P = (const float*)d_in[3];
  float* out = (float*)d_out;

  // Workspace carve (~42.3 MB)
  float* ws = (float*)d_ws;
  float* dashF = ws;                       // B*H*L*M fp32 (dead after chunk_sum)
  float* ksp = dashF + (size_t)B_ * H_ * L_ * M_;        // B*H*C*M
  float* kdiag = ksp + (size_t)B_ * H_ * C_ * M_;        // B*H*L
  float* kmax = kdiag + (size_t)B_ * H_ * L_;            // B*H
  unsigned short* qp16 = (unsigned short*)(kmax + 16);   // B*H*L*M bf16
  unsigned short* kp16 = qp16 + (size_t)B_ * H_ * L_ * M_;
  unsigned short* kvc16 = kp16 + (size_t)B_ * H_ * L_ * M_;  // B*H*C*D*M
  unsigned short* kvp16 = (unsigned short*)dashF;        // alias (dash dead)

  init_kmax_kernel<<<1, 64, 0, stream>>>(kmax);
  feat_q_kernel<<<B_ * H_ * C_, 256, 0, stream>>>(q, P, qp16);
  feat_k_kernel<<<B_ * H_ * C_, 256, 0, stream>>>(k, P, dashF, kdiag, kmax);
  chunk_sum_kernel<<<B_ * H_ * C_, 256, 0, stream>>>(dashF, kdiag, kmax, v,
                                                     kp16, kvc16, ksp);
  prefix_kernel<<<B_ * H_ * 32, 256, 0, stream>>>(kvc16, kvp16, ksp);
  intra_kernel<<<B_ * H_ * C_, 256, 0, stream>>>(qp16, kp16, v, kvp16, ksp, out);
}

// Round 4
// 73.272 us; speedup vs baseline: 5.3684x; 1.0829x over previous
//
#include <hip/hip_runtime.h>
#include <math.h>

typedef __attribute__((ext_vector_type(8))) short short8;
typedef __attribute__((ext_vector_type(4))) float f32x4;
typedef __attribute__((ext_vector_type(4))) unsigned short u16x4;

// Problem constants: B=2, L=2048, H=8, D=64, M=128.
constexpr int B_ = 2, L_ = 2048, H_ = 8, D_ = 64, M_ = 128;
constexpr int T_ = 64;            // chunk length
constexpr int C_ = L_ / T_;       // 32 chunks
constexpr float DN_ = 0.35355339059327373f;     // 64^-0.25
constexpr float RATIO_ = 0.08838834764831845f;  // 1/sqrt(128)
constexpr float EPSV_ = 1e-6f;

__device__ inline unsigned short f2bf(float x) {  // RNE float->bf16
  const unsigned u = __float_as_uint(x);
  return (unsigned short)((u + 0x7fffu + ((u >> 16) & 1u)) >> 16);
}
__device__ inline float bf2f(unsigned short h) {
  return __uint_as_float(((unsigned)h) << 16);
}

// Fused Q feature map + K max pre-pass. Grid 1024: bid<512 -> Q path
// (full pipeline, bf16 q' out); bid>=512 -> K path (dash GEMM, keep only
// per-block max -> blockmax, no global writes of dash).
__global__ __launch_bounds__(256) void featqk_kernel(
    const float* __restrict__ q, const float* __restrict__ k,
    const float* __restrict__ P, unsigned short* __restrict__ qp16,
    float* __restrict__ blockmax) {
  __shared__ __align__(16) float x_s[T_][68];
  __shared__ __align__(16) float p_s[D_][M_];
  __shared__ float red_s[4];
  const int bid = blockIdx.x;
  const bool isQ = bid < 512;
  const int sub = isQ ? bid : bid - 512;
  const int lt = sub % C_;
  const int bh = sub / C_;
  const int b = bh >> 3, h = bh & 7;
  const float* x = isQ ? q : k;
  const int tid = threadIdx.x;
  const int lg = tid >> 4, mg = tid & 15;
  const int l0 = lg * 4, m0 = mg * 8;

  for (int i4 = tid; i4 < T_ * 16; i4 += 256) {
    const int r = i4 >> 4, d0 = (i4 & 15) * 4;
    float4 t4 = *reinterpret_cast<const float4*>(
        &x[((size_t)(b * L_ + lt * T_ + r) * H_ + h) * D_ + d0]);
    t4.x *= DN_; t4.y *= DN_; t4.z *= DN_; t4.w *= DN_;
    *reinterpret_cast<float4*>(&x_s[r][d0]) = t4;
  }
  for (int i = tid; i < M_ * D_ / 4; i += 256) {
    const int m = i >> 4, d0 = (i & 15) * 4;
    const float4 t4 = *reinterpret_cast<const float4*>(&P[m * D_ + d0]);
    p_s[d0][m] = t4.x; p_s[d0 + 1][m] = t4.y;
    p_s[d0 + 2][m] = t4.z; p_s[d0 + 3][m] = t4.w;
  }
  __syncthreads();

  float acc[4][8];
#pragma unroll
  for (int i = 0; i < 4; ++i)
#pragma unroll
    for (int j = 0; j < 8; ++j) acc[i][j] = 0.f;

#pragma unroll
  for (int d4 = 0; d4 < 16; ++d4) {
    float4 xv[4];
#pragma unroll
    for (int i = 0; i < 4; ++i)
      xv[i] = *reinterpret_cast<const float4*>(&x_s[l0 + i][d4 * 4]);
#pragma unroll
    for (int dd = 0; dd < 4; ++dd) {
      const int d = d4 * 4 + dd;
      const float4 pv0 = *reinterpret_cast<const float4*>(&p_s[d][m0]);
      const float4 pv1 = *reinterpret_cast<const float4*>(&p_s[d][m0 + 4]);
#pragma unroll
      for (int i = 0; i < 4; ++i) {
        const float xd = dd == 0 ? xv[i].x : dd == 1 ? xv[i].y
                       : dd == 2 ? xv[i].z : xv[i].w;
        acc[i][0] += xd * pv0.x; acc[i][1] += xd * pv0.y;
        acc[i][2] += xd * pv0.z; acc[i][3] += xd * pv0.w;
        acc[i][4] += xd * pv1.x; acc[i][5] += xd * pv1.y;
        acc[i][6] += xd * pv1.z; acc[i][7] += xd * pv1.w;
      }
    }
  }

  if (isQ) {
    float diag[4];
#pragma unroll
    for (int i = 0; i < 4; ++i) {
      const float4 xv = *reinterpret_cast<const float4*>(&x_s[l0 + i][mg * 4]);
      float s = xv.x * xv.x + xv.y * xv.y + xv.z * xv.z + xv.w * xv.w;
#pragma unroll
      for (int off = 1; off < 16; off <<= 1) s += __shfl_xor(s, off, 64);
      diag[i] = 0.5f * s;
    }
    unsigned short* outr = qp16 + ((size_t)bh * L_ + lt * T_) * M_;
#pragma unroll
    for (int i = 0; i < 4; ++i) {
      float mx = acc[i][0];
#pragma unroll
      for (int j = 1; j < 8; ++j) mx = fmaxf(mx, acc[i][j]);
#pragma unroll
      for (int off = 1; off < 16; off <<= 1)
        mx = fmaxf(mx, __shfl_xor(mx, off, 64));
      const float sub2 = diag[i] + mx;
      short8 o;
#pragma unroll
      for (int j = 0; j < 8; ++j)
        o[j] = (short)f2bf(RATIO_ * (expf(acc[i][j] - sub2) + EPSV_));
      *reinterpret_cast<short8*>(&outr[(l0 + i) * M_ + m0]) = o;
    }
  } else {
    float bm = -INFINITY;
#pragma unroll
    for (int i = 0; i < 4; ++i)
#pragma unroll
      for (int j = 0; j < 8; ++j) bm = fmaxf(bm, acc[i][j]);
#pragma unroll
    for (int off = 1; off < 64; off <<= 1) bm = fmaxf(bm, __shfl_xor(bm, off, 64));
    if ((tid & 63) == 0) red_s[tid >> 6] = bm;
    __syncthreads();
    if (tid == 0)
      blockmax[sub] = fmaxf(fmaxf(red_s[0], red_s[1]),
                            fmaxf(red_s[2], red_s[3]));
  }
}

// Fused: recompute K dash (LDS GEMM), k' = ratio*(exp(dash-diag-kmax)+eps)
// -> bf16 kp16 + LDS; then chunk sums KV^T[d][m] (bf16) and ks[m] (fp32).
// LDS phases alias: P <-> kp, x <-> v  (50KB total).
__global__ __launch_bounds__(256) void chunk_sum_kernel(
    const float* __restrict__ k, const float* __restrict__ P,
    const float* __restrict__ blockmax, const float* __restrict__ v,
    unsigned short* __restrict__ kp16, unsigned short* __restrict__ kvc16,
    float* __restrict__ ksc) {
  __shared__ __align__(16) float smem[64 * 68 + D_ * M_];  // 50.2KB
  float* x_s = smem;           // [64][68] fp32 k-tile; later v tile [64][68]
  float* p_s = smem + 64 * 68; // [d][m] fp32 P; later kp_s[64][128]
  float* kp_s = p_s;
  float* v_s = x_s;
  __shared__ float kmx_s;

  const int bid = blockIdx.x;
  const int c = bid % C_, bh = bid / C_;
  const int b = bh >> 3, h = bh & 7;
  const int tid = threadIdx.x;
  const int lg = tid >> 4, mg = tid & 15;
  const int l0 = lg * 4, m0 = mg * 8;

  // stage k tile + P; reduce blockmax -> kmx_s
  for (int i4 = tid; i4 < T_ * 16; i4 += 256) {
    const int r = i4 >> 4, d0 = (i4 & 15) * 4;
    float4 t4 = *reinterpret_cast<const float4*>(
        &k[((size_t)(b * L_ + c * T_ + r) * H_ + h) * D_ + d0]);
    t4.x *= DN_; t4.y *= DN_; t4.z *= DN_; t4.w *= DN_;
    *reinterpret_cast<float4*>(&x_s[r * 68 + d0]) = t4;
  }
  for (int i = tid; i < M_ * D_ / 4; i += 256) {
    const int m = i >> 4, d0 = (i & 15) * 4;
    const float4 t4 = *reinterpret_cast<const float4*>(&P[m * D_ + d0]);
    p_s[d0 * M_ + m] = t4.x; p_s[(d0 + 1) * M_ + m] = t4.y;
    p_s[(d0 + 2) * M_ + m] = t4.z; p_s[(d0 + 3) * M_ + m] = t4.w;
  }
  if (tid < 64) {
    float bm = (tid < C_) ? blockmax[bh * C_ + tid] : -INFINITY;
#pragma unroll
    for (int off = 16; off; off >>= 1) bm = fmaxf(bm, __shfl_xor(bm, off, 64));
    if (tid == 0) kmx_s = bm;
  }
  __syncthreads();

  float acc[4][8];
#pragma unroll
  for (int i = 0; i < 4; ++i)
#pragma unroll
    for (int j = 0; j < 8; ++j) acc[i][j] = 0.f;
#pragma unroll
  for (int d4 = 0; d4 < 16; ++d4) {
    float4 xv[4];
#pragma unroll
    for (int i = 0; i < 4; ++i)
      xv[i] = *reinterpret_cast<const float4*>(&x_s[(l0 + i) * 68 + d4 * 4]);
#pragma unroll
    for (int dd = 0; dd < 4; ++dd) {
      const int d = d4 * 4 + dd;
      const float4 pv0 = *reinterpret_cast<const float4*>(&p_s[d * M_ + m0]);
      const float4 pv1 = *reinterpret_cast<const float4*>(&p_s[d * M_ + m0 + 4]);
#pragma unroll
      for (int i = 0; i < 4; ++i) {
        const float xd = dd == 0 ? xv[i].x : dd == 1 ? xv[i].y
                       : dd == 2 ? xv[i].z : xv[i].w;
        acc[i][0] += xd * pv0.x; acc[i][1] += xd * pv0.y;
        acc[i][2] += xd * pv0.z; acc[i][3] += xd * pv0.w;
        acc[i][4] += xd * pv1.x; acc[i][5] += xd * pv1.y;
        acc[i][6] += xd * pv1.z; acc[i][7] += xd * pv1.w;
      }
    }
  }
  float diag[4];
#pragma unroll
  for (int i = 0; i < 4; ++i) {
    const float4 xv = *reinterpret_cast<const float4*>(&x_s[(l0 + i) * 68 + mg * 4]);
    float s = xv.x * xv.x + xv.y * xv.y + xv.z * xv.z + xv.w * xv.w;
#pragma unroll
    for (int off = 1; off < 16; off <<= 1) s += __shfl_xor(s, off, 64);
    diag[i] = 0.5f * s;
  }
  const float kmx = kmx_s;
  __syncthreads();  // all reads of p_s / x_s done; safe to overwrite

  // kp from acc -> LDS (aliases p_s) + bf16 global; v tile -> v_s (aliases x_s)
  unsigned short* kpo = kp16 + ((size_t)bh * L_ + c * T_) * M_;
#pragma unroll
  for (int i = 0; i < 4; ++i) {
    const float sub2 = diag[i] + kmx;
    float kv[8];
    short8 o;
#pragma unroll
    for (int j = 0; j < 8; ++j) {
      kv[j] = RATIO_ * (expf(acc[i][j] - sub2) + EPSV_);
      o[j] = (short)f2bf(kv[j]);
    }
    f32x4 k0 = {kv[0], kv[1], kv[2], kv[3]};
    f32x4 k1 = {kv[4], kv[5], kv[6], kv[7]};
    *reinterpret_cast<f32x4*>(&kp_s[(l0 + i) * M_ + m0]) = k0;
    *reinterpret_cast<f32x4*>(&kp_s[(l0 + i) * M_ + m0 + 4]) = k1;
    *reinterpret_cast<short8*>(&kpo[(l0 + i) * M_ + m0]) = o;
  }
  for (int i4 = tid; i4 < T_ * 16; i4 += 256) {
    const int t = i4 >> 4, d0 = (i4 & 15) * 4;
    *reinterpret_cast<f32x4*>(&v_s[t * 68 + d0]) =
        *reinterpret_cast<const f32x4*>(
            &v[((size_t)(b * L_ + c * T_ + t) * H_ + h) * D_ + d0]);
  }
  __syncthreads();

  // KV^T[d][m] chunk sums + ks[m]
  const int mgr = tid & 15, dgr = tid >> 4;
  const int mm0 = mgr * 4, d0 = dgr * 4;
  float kacc[4][8];
#pragma unroll
  for (int i = 0; i < 4; ++i)
#pragma unroll
    for (int j = 0; j < 8; ++j) kacc[i][j] = 0.f;
  for (int t = 0; t < T_; ++t) {
    const f32x4 vv = *reinterpret_cast<const f32x4*>(&v_s[t * 68 + d0]);
    const f32x4 a0 = *reinterpret_cast<const f32x4*>(&kp_s[t * M_ + mm0]);
    const f32x4 a1 = *reinterpret_cast<const f32x4*>(&kp_s[t * M_ + mm0 + 64]);
#pragma unroll
    for (int i = 0; i < 4; ++i)
#pragma unroll
      for (int j = 0; j < 4; ++j) {
        kacc[i][j] += vv[i] * a0[j];
        kacc[i][j + 4] += vv[i] * a1[j];
      }
  }
  unsigned short* ob = kvc16 + (size_t)(bh * C_ + c) * (M_ * D_);
#pragma unroll
  for (int i = 0; i < 4; ++i) {
    u16x4 p0, p1;
#pragma unroll
    for (int j = 0; j < 4; ++j) {
      p0[j] = f2bf(kacc[i][j]);
      p1[j] = f2bf(kacc[i][j + 4]);
    }
    *reinterpret_cast<u16x4*>(&ob[(d0 + i) * M_ + mm0]) = p0;
    *reinterpret_cast<u16x4*>(&ob[(d0 + i) * M_ + mm0 + 64]) = p1;
  }
  if (tid < M_) {
    float s = 0.f;
    for (int t = 0; t < T_; ++t) s += kp_s[t * M_ + tid];
    ksc[(size_t)(bh * C_ + c) * M_ + tid] = s;
  }
}

// Exclusive prefix across chunks: kvc16 (bf16) -> fp32 scan -> kvp16 (bf16);
// ksc fp32 scan in place.
__global__ __launch_bounds__(256) void prefix_kernel(
    const unsigned short* __restrict__ kvc16,
    unsigned short* __restrict__ kvp16, float* __restrict__ ksc) {
  const int bid = blockIdx.x;  // B*H*32
  const int ej = bid & 31, bh = bid >> 5;
  const int e = ej * 256 + threadIdx.x;  // element of [D][M]
  float vals[C_];
#pragma unroll
  for (int c = 0; c < C_; ++c)
    vals[c] = bf2f(kvc16[(size_t)(bh * C_ + c) * (M_ * D_) + e]);
  float run = 0.f;
#pragma unroll
  for (int c = 0; c < C_; ++c) { const float t = vals[c]; vals[c] = run; run += t; }
#pragma unroll
  for (int c = 0; c < C_; ++c)
    kvp16[(size_t)(bh * C_ + c) * (M_ * D_) + e] = f2bf(vals[c]);
  if (ej == 0 && threadIdx.x < M_) {
    const int m = threadIdx.x;
    float ks[C_];
#pragma unroll
    for (int c = 0; c < C_; ++c) ks[c] = ksc[(size_t)(bh * C_ + c) * M_ + m];
    float rs = 0.f;
#pragma unroll
    for (int c = 0; c < C_; ++c) { const float t = ks[c]; ks[c] = rs; rs += t; }
#pragma unroll
    for (int c = 0; c < C_; ++c) ksc[(size_t)(bh * C_ + c) * M_ + m] = ks[c];
  }
}

// Intra-chunk, MFMA bf16 (unchanged from round 3). 4 waves; wave w owns rows
// rblk=(w>>1)*32, S-cols / out-d cols (w&1)*32. All GEMMs NT.
__global__ __launch_bounds__(256) void intra_kernel(
    const unsigned short* __restrict__ qp16,
    const unsigned short* __restrict__ kp16, const float* __restrict__ v,
    const unsigned short* __restrict__ kvp16, const float* __restrict__ ksp,
    float* __restrict__ out) {
  __shared__ __align__(16) unsigned short qp_s[T_][136];
  __shared__ __align__(16) unsigned short kp_s[T_][136];
  __shared__ __align__(16) unsigned short kvp_s[D_][136];
  __shared__ __align__(16) unsigned short S_s[T_][72];
  __shared__ __align__(16) unsigned short vt_s[D_][72];
  __shared__ float ksp_s[M_];
  __shared__ float denp_s[4][T_];
  __shared__ float den_s[T_];

  const int bid = blockIdx.x;
  const int c = bid % C_, bh = bid / C_;
  const int b = bh >> 3, h = bh & 7;
  const int tid = threadIdx.x;
  const int w = tid >> 6, lane = tid & 63;
  const int l15 = lane & 15, l16 = lane >> 4;

  const unsigned short* qpt = qp16 + ((size_t)bh * L_ + c * T_) * M_;
  const unsigned short* kpt = kp16 + ((size_t)bh * L_ + c * T_) * M_;
  const unsigned short* kvt = kvp16 + (size_t)(bh * C_ + c) * (M_ * D_);

  for (int i8 = tid; i8 < T_ * 16; i8 += 256) {
    const int r = i8 >> 4, m0 = (i8 & 15) * 8;
    *reinterpret_cast<short8*>(&qp_s[r][m0]) =
        *reinterpret_cast<const short8*>(&qpt[r * M_ + m0]);
    *reinterpret_cast<short8*>(&kp_s[r][m0]) =
        *reinterpret_cast<const short8*>(&kpt[r * M_ + m0]);
    *reinterpret_cast<short8*>(&kvp_s[r][m0]) =
        *reinterpret_cast<const short8*>(&kvt[r * M_ + m0]);
  }
  for (int i = tid; i < T_ * D_; i += 256) {
    const int t = i & 63, d = i >> 6;
    vt_s[d][t] = f2bf(v[((size_t)(b * L_ + c * T_ + t) * H_ + h) * D_ + d]);
  }
  if (tid < M_) ksp_s[tid] = ksp[(size_t)(bh * C_ + c) * M_ + tid];
  __syncthreads();

  const int rblk = (w >> 1) * 32, cblk = (w & 1) * 32;
  f32x4 Sacc[2][2];
#pragma unroll
  for (int i = 0; i < 2; ++i)
#pragma unroll
    for (int j = 0; j < 2; ++j) Sacc[i][j] = {0.f, 0.f, 0.f, 0.f};

#pragma unroll
  for (int kk = 0; kk < 4; ++kk) {
    short8 af[2], bf[2];
#pragma unroll
    for (int ti = 0; ti < 2; ++ti)
      af[ti] = *reinterpret_cast<const short8*>(
          &qp_s[rblk + ti * 16 + l15][kk * 32 + l16 * 8]);
#pragma unroll
    for (int tj = 0; tj < 2; ++tj)
      bf[tj] = *reinterpret_cast<const short8*>(
          &kp_s[cblk + tj * 16 + l15][kk * 32 + l16 * 8]);
#pragma unroll
    for (int ti = 0; ti < 2; ++ti)
#pragma unroll
      for (int tj = 0; tj < 2; ++tj)
        Sacc[ti][tj] = __builtin_amdgcn_mfma_f32_16x16x32_bf16(
            af[ti], bf[tj], Sacc[ti][tj], 0, 0, 0);
  }
#pragma unroll
  for (int ti = 0; ti < 2; ++ti)
#pragma unroll
    for (int tj = 0; tj < 2; ++tj)
#pragma unroll
      for (int j = 0; j < 4; ++j) {
        const int row = rblk + ti * 16 + l16 * 4 + j;
        const int col = cblk + tj * 16 + l15;
        const float sv = (col <= row) ? Sacc[ti][tj][j] : 0.f;
        S_s[row][col] = f2bf(sv);
      }
  __syncthreads();

  {
    const int t = lane;
    float p = 0.f;
    if (w == 0) {
      for (int tp = 0; tp < 32; ++tp) p += bf2f(S_s[t][tp]);
    } else if (w == 1) {
      for (int tp = 32; tp < 64; ++tp) p += bf2f(S_s[t][tp]);
    } else if (w == 2) {
      for (int m = 0; m < 64; ++m) p += bf2f(qp_s[t][m]) * ksp_s[m];
    } else {
      for (int m = 64; m < 128; ++m) p += bf2f(qp_s[t][m]) * ksp_s[m];
    }
    denp_s[w][t] = p;
  }
  __syncthreads();
  if (tid < T_)
    den_s[tid] = denp_s[0][tid] + denp_s[1][tid] + denp_s[2][tid] + denp_s[3][tid];
  __syncthreads();

  const int dblk = (w & 1) * 32;
  f32x4 Nacc[2][2];
#pragma unroll
  for (int i = 0; i < 2; ++i)
#pragma unroll
    for (int j = 0; j < 2; ++j) Nacc[i][j] = {0.f, 0.f, 0.f, 0.f};

#pragma unroll
  for (int kk = 0; kk < 2; ++kk) {
    short8 af[2], bf[2];
#pragma unroll
    for (int ti = 0; ti < 2; ++ti)
      af[ti] = *reinterpret_cast<const short8*>(
          &S_s[rblk + ti * 16 + l15][kk * 32 + l16 * 8]);
#pragma unroll
    for (int tj = 0; tj < 2; ++tj)
      bf[tj] = *reinterpret_cast<const short8*>(
          &vt_s[dblk + tj * 16 + l15][kk * 32 + l16 * 8]);
#pragma unroll
    for (int ti = 0; ti < 2; ++ti)
#pragma unroll
      for (int tj = 0; tj < 2; ++tj)
        Nacc[ti][tj] = __builtin_amdgcn_mfma_f32_16x16x32_bf16(
            af[ti], bf[tj], Nacc[ti][tj], 0, 0, 0);
  }
#pragma unroll
  for (int kk = 0; kk < 4; ++kk) {
    short8 af[2], bf[2];
#pragma unroll
    for (int ti = 0; ti < 2; ++ti)
      af[ti] = *reinterpret_cast<const short8*>(
          &qp_s[rblk + ti * 16 + l15][kk * 32 + l16 * 8]);
#pragma unroll
    for (int tj = 0; tj < 2; ++tj)
      bf[tj] = *reinterpret_cast<const short8*>(
          &kvp_s[dblk + tj * 16 + l15][kk * 32 + l16 * 8]);
#pragma unroll
    for (int ti = 0; ti < 2; ++ti)
#pragma unroll
      for (int tj = 0; tj < 2; ++tj)
        Nacc[ti][tj] = __builtin_amdgcn_mfma_f32_16x16x32_bf16(
            af[ti], bf[tj], Nacc[ti][tj], 0, 0, 0);
  }

#pragma unroll
  for (int ti = 0; ti < 2; ++ti)
#pragma unroll
    for (int j = 0; j < 4; ++j) {
      const int row = rblk + ti * 16 + l16 * 4 + j;
      const float r = 1.f / den_s[row];
      float* orow = out + ((size_t)(b * L_ + c * T_ + row) * H_ + h) * D_;
#pragma unroll
      for (int tj = 0; tj < 2; ++tj) {
        const int col = dblk + tj * 16 + l15;
        orow[col] = Nacc[ti][tj][j] * r;
      }
    }
}

extern "C" void kernel_launch(void* const* d_in, const int* in_sizes, int n_in,
                              void* d_out, int out_size, void* d_ws,
                              size_t ws_size, hipStream_t stream) {
  const float* q = (const float*)d_in[0];
  const float* k = (const float*)d_in[1];
  const float* v = (const float*)d_in[2];
  const float* P = (const float*)d_in[3];
  float* out = (float*)d_out;

  // Workspace carve (~34 MB)
  float* ws = (float*)d_ws;
  float* blockmax = ws;                              // 512
  float* ksp = blockmax + 512;                       // B*H*C*M = 65536
  unsigned short* qp16 = (unsigned short*)(ksp + (size_t)B_ * H_ * C_ * M_);
  unsigned short* kp16 = qp16 + (size_t)B_ * H_ * L_ * M_;
  unsigned short* kvc16 = kp16 + (size_t)B_ * H_ * L_ * M_;
  unsigned short* kvp16 = kvc16 + (size_t)B_ * H_ * C_ * D_ * M_;

  featqk_kernel<<<2 * B_ * H_ * C_, 256, 0, stream>>>(q, k, P, qp16, blockmax);
  chunk_sum_kernel<<<B_ * H_ * C_, 256, 0, stream>>>(k, P, blockmax, v, kp16,
                                                     kvc16, ksp);
  prefix_kernel<<<B_ * H_ * 32, 256, 0, stream>>>(kvc16, kvp16, ksp);
  intra_kernel<<<B_ * H_ * C_, 256, 0, stream>>>(qp16, kp16, v, kvp16, ksp, out);
}

// Round 6
// 48.222 us; speedup vs baseline: 8.1571x; 1.5195x over previous
//
#include <hip/hip_runtime.h>
#include <math.h>

typedef __attribute__((ext_vector_type(8))) short short8;
typedef __attribute__((ext_vector_type(4))) float f32x4;
typedef __attribute__((ext_vector_type(4))) unsigned short u16x4;

// Problem constants: B=2, L=2048, H=8, D=64, M=128.
constexpr int B_ = 2, L_ = 2048, H_ = 8, D_ = 64, M_ = 128;
constexpr int T_ = 64;            // chunk length
constexpr int C_ = L_ / T_;       // 32 chunks
constexpr float DN_ = 0.35355339059327373f;     // 64^-0.25
constexpr float RATIO_ = 0.08838834764831845f;  // 1/sqrt(128)
constexpr float EPSV_ = 1e-6f;
constexpr float REPS_ = RATIO_ * EPSV_;   // ratio*eps: the k' additive floor
constexpr float KEPS_ = 64.0f * REPS_;    // per-chunk ks eps mass

// eps decomposition (round-5 post-mortem): k'_true = sc_c * kpE + REPS_,
// kpE = ratio*exp(dash-diag-lmax_c), sc_c = exp(lmax_c - kmax). The REPS_
// floor is NOT negligible relative to den (exp-mass ~ eps-mass globally), so
// it is carried EXACTLY as rank-1 corrections: ks += 64*REPS_/chunk,
// KV += REPS_*Vsum_c[d], S[t][t'] += REPS_*qsum[t] (unmasked entries).

__device__ inline unsigned short f2bf(float x) {  // RNE float->bf16
  const unsigned u = __float_as_uint(x);
  return (unsigned short)((u + 0x7fffu + ((u >> 16) & 1u)) >> 16);
}
__device__ inline float bf2f(unsigned short h) {
  return __uint_as_float(((unsigned)h) << 16);
}

// Fused feature kernel. Grid 1024. bid<512: Q path -> qp16 (bf16, with +eps).
// bid>=512: K path -> kp16 = kpE (NO eps, chunk-local units), blockmax[bh][c],
// KVE chunk sums kvc16 [d][m], ksE sums ksc[m], vt16 (bf16 V^T), vsum_c[d].
__global__ __launch_bounds__(256) void feat_kernel(
    const float* __restrict__ q, const float* __restrict__ k,
    const float* __restrict__ P, const float* __restrict__ v,
    unsigned short* __restrict__ qp16, unsigned short* __restrict__ kp16,
    unsigned short* __restrict__ kvc16, float* __restrict__ ksc,
    unsigned short* __restrict__ vt16, float* __restrict__ blockmax,
    float* __restrict__ vsum) {
  __shared__ __align__(16) unsigned short xh_s[T_][72];
  __shared__ __align__(16) unsigned short xl_s[T_][72];
  __shared__ __align__(16) unsigned short ph_s[M_][72];
  __shared__ __align__(16) unsigned short pl_s[M_][72];
  __shared__ float diag_s[T_];
  __shared__ float wred_s[2][T_];
  __shared__ float red4_s[4];
  unsigned short (*kpT_s)[72] = ph_s;  // K phase-2 alias: [128][72] k'^T [m][t]
  unsigned short (*vt_s)[72] = xh_s;   // K phase-2 alias: [64][72]  V^T  [d][t]

  const int bid = blockIdx.x;
  const bool isQ = bid < 512;
  const int sub = isQ ? bid : bid - 512;
  const int c = sub % C_, bh = sub / C_;
  const int b = bh >> 3, h = bh & 7;
  const float* x = isQ ? q : k;
  const int tid = threadIdx.x;
  const int w = tid >> 6, lane = tid & 63;
  const int l15 = lane & 15, l16 = lane >> 4;

  if (tid < T_) diag_s[tid] = 0.f;
  __syncthreads();
  for (int i4 = tid; i4 < T_ * 16; i4 += 256) {
    const int r = i4 >> 4, d0 = (i4 & 15) * 4;
    f32x4 t4 = *reinterpret_cast<const f32x4*>(
        &x[((size_t)(b * L_ + c * T_ + r) * H_ + h) * D_ + d0]);
    u16x4 hi, lo;
    float sq = 0.f;
#pragma unroll
    for (int j = 0; j < 4; ++j) {
      const float xv = t4[j] * DN_;
      sq += xv * xv;
      const unsigned short hb = f2bf(xv);
      hi[j] = hb;
      lo[j] = f2bf(xv - bf2f(hb));
    }
    *reinterpret_cast<u16x4*>(&xh_s[r][d0]) = hi;
    *reinterpret_cast<u16x4*>(&xl_s[r][d0]) = lo;
    atomicAdd(&diag_s[r], sq);
  }
  for (int i4 = tid; i4 < M_ * 16; i4 += 256) {
    const int m = i4 >> 4, d0 = (i4 & 15) * 4;
    const f32x4 t4 = *reinterpret_cast<const f32x4*>(&P[m * D_ + d0]);
    u16x4 hi, lo;
#pragma unroll
    for (int j = 0; j < 4; ++j) {
      const unsigned short hb = f2bf(t4[j]);
      hi[j] = hb;
      lo[j] = f2bf(t4[j] - bf2f(hb));
    }
    *reinterpret_cast<u16x4*>(&ph_s[m][d0]) = hi;
    *reinterpret_cast<u16x4*>(&pl_s[m][d0]) = lo;
  }
  __syncthreads();

  // dash via split-bf16 MFMA (al*bh + ah*bl + ah*bh; al*bl dropped ~2^-18)
  const int rblk = (w >> 1) * 32, cblk = (w & 1) * 64;
  f32x4 acc[2][4];
#pragma unroll
  for (int i = 0; i < 2; ++i)
#pragma unroll
    for (int j = 0; j < 4; ++j) acc[i][j] = {0.f, 0.f, 0.f, 0.f};
#pragma unroll
  for (int kk = 0; kk < 2; ++kk) {
    short8 ah[2], al[2], bh8[4], bl8[4];
#pragma unroll
    for (int ti = 0; ti < 2; ++ti) {
      ah[ti] = *reinterpret_cast<const short8*>(
          &xh_s[rblk + ti * 16 + l15][kk * 32 + l16 * 8]);
      al[ti] = *reinterpret_cast<const short8*>(
          &xl_s[rblk + ti * 16 + l15][kk * 32 + l16 * 8]);
    }
#pragma unroll
    for (int tj = 0; tj < 4; ++tj) {
      bh8[tj] = *reinterpret_cast<const short8*>(
          &ph_s[cblk + tj * 16 + l15][kk * 32 + l16 * 8]);
      bl8[tj] = *reinterpret_cast<const short8*>(
          &pl_s[cblk + tj * 16 + l15][kk * 32 + l16 * 8]);
    }
#pragma unroll
    for (int ti = 0; ti < 2; ++ti)
#pragma unroll
      for (int tj = 0; tj < 4; ++tj) {
        acc[ti][tj] = __builtin_amdgcn_mfma_f32_16x16x32_bf16(
            al[ti], bh8[tj], acc[ti][tj], 0, 0, 0);
        acc[ti][tj] = __builtin_amdgcn_mfma_f32_16x16x32_bf16(
            ah[ti], bl8[tj], acc[ti][tj], 0, 0, 0);
        acc[ti][tj] = __builtin_amdgcn_mfma_f32_16x16x32_bf16(
            ah[ti], bh8[tj], acc[ti][tj], 0, 0, 0);
      }
  }

  if (isQ) {
    float rmax[2][4];
#pragma unroll
    for (int ti = 0; ti < 2; ++ti)
#pragma unroll
      for (int j = 0; j < 4; ++j) {
        float m0 = fmaxf(fmaxf(acc[ti][0][j], acc[ti][1][j]),
                         fmaxf(acc[ti][2][j], acc[ti][3][j]));
#pragma unroll
        for (int off = 1; off < 16; off <<= 1)
          m0 = fmaxf(m0, __shfl_xor(m0, off, 64));
        rmax[ti][j] = m0;
      }
    if (l15 == 0) {
#pragma unroll
      for (int ti = 0; ti < 2; ++ti)
#pragma unroll
        for (int j = 0; j < 4; ++j)
          wred_s[w & 1][rblk + ti * 16 + l16 * 4 + j] = rmax[ti][j];
    }
    __syncthreads();
    unsigned short* outr = qp16 + ((size_t)bh * L_ + c * T_) * M_;
#pragma unroll
    for (int ti = 0; ti < 2; ++ti)
#pragma unroll
      for (int j = 0; j < 4; ++j) {
        const int row = rblk + ti * 16 + l16 * 4 + j;
        const float sub2 =
            0.5f * diag_s[row] + fmaxf(wred_s[0][row], wred_s[1][row]);
#pragma unroll
        for (int tj = 0; tj < 4; ++tj) {
          const int col = cblk + tj * 16 + l15;
          outr[row * M_ + col] =
              f2bf(RATIO_ * (expf(acc[ti][tj][j] - sub2) + EPSV_));
        }
      }
  } else {
    float bm = -INFINITY;
#pragma unroll
    for (int ti = 0; ti < 2; ++ti)
#pragma unroll
      for (int tj = 0; tj < 4; ++tj)
#pragma unroll
        for (int j = 0; j < 4; ++j) bm = fmaxf(bm, acc[ti][tj][j]);
#pragma unroll
    for (int off = 1; off < 64; off <<= 1)
      bm = fmaxf(bm, __shfl_xor(bm, off, 64));
    if (lane == 0) red4_s[w] = bm;
    __syncthreads();  // red4 visible AND all MFMA reads of ph/xh complete
    const float lmax =
        fmaxf(fmaxf(red4_s[0], red4_s[1]), fmaxf(red4_s[2], red4_s[3]));
    if (tid == 0) blockmax[sub] = lmax;

    // kpE (NO eps) -> global kp16 + LDS kpT; stage V^T
    unsigned short* kpr = kp16 + ((size_t)bh * L_ + c * T_) * M_;
#pragma unroll
    for (int ti = 0; ti < 2; ++ti)
#pragma unroll
      for (int j = 0; j < 4; ++j) {
        const int row = rblk + ti * 16 + l16 * 4 + j;
        const float sub2 = 0.5f * diag_s[row] + lmax;
#pragma unroll
        for (int tj = 0; tj < 4; ++tj) {
          const int col = cblk + tj * 16 + l15;
          const unsigned short us = f2bf(RATIO_ * expf(acc[ti][tj][j] - sub2));
          kpr[row * M_ + col] = us;
          kpT_s[col][row] = us;
        }
      }
    for (int i = tid; i < T_ * D_; i += 256) {
      const int t = i & 63, d = i >> 6;
      vt_s[d][t] = f2bf(v[((size_t)(b * L_ + c * T_ + t) * H_ + h) * D_ + d]);
    }
    __syncthreads();

    unsigned short* vg = vt16 + (size_t)(bh * C_ + c) * (D_ * T_);
    for (int i8 = tid; i8 < D_ * 8; i8 += 256) {
      const int d = i8 >> 3, t0 = (i8 & 7) * 8;
      *reinterpret_cast<short8*>(&vg[d * T_ + t0]) =
          *reinterpret_cast<const short8*>(&vt_s[d][t0]);
    }
    // ksE[m] and Vsum[d] for the eps corrections downstream
    if (tid < M_) {
      float s = 0.f;
      for (int t = 0; t < T_; ++t) s += bf2f(kpT_s[tid][t]);
      ksc[(size_t)(bh * C_ + c) * M_ + tid] = s;
    }
    if (tid >= 128 && tid < 128 + D_) {
      const int d = tid - 128;
      float s = 0.f;
      for (int t = 0; t < T_; ++t) s += bf2f(vt_s[d][t]);
      vsum[(size_t)(bh * C_ + c) * D_ + d] = s;
    }
    // KVE^T[d][m] = sum_t v[t,d]*kpE[t,m]
    f32x4 acc2[2][4];
#pragma unroll
    for (int i = 0; i < 2; ++i)
#pragma unroll
      for (int j = 0; j < 4; ++j) acc2[i][j] = {0.f, 0.f, 0.f, 0.f};
#pragma unroll
    for (int kk = 0; kk < 2; ++kk) {
      short8 av[2], bv[4];
#pragma unroll
      for (int ti = 0; ti < 2; ++ti)
        av[ti] = *reinterpret_cast<const short8*>(
            &vt_s[rblk + ti * 16 + l15][kk * 32 + l16 * 8]);
#pragma unroll
      for (int tj = 0; tj < 4; ++tj)
        bv[tj] = *reinterpret_cast<const short8*>(
            &kpT_s[cblk + tj * 16 + l15][kk * 32 + l16 * 8]);
#pragma unroll
      for (int ti = 0; ti < 2; ++ti)
#pragma unroll
        for (int tj = 0; tj < 4; ++tj)
          acc2[ti][tj] = __builtin_amdgcn_mfma_f32_16x16x32_bf16(
              av[ti], bv[tj], acc2[ti][tj], 0, 0, 0);
    }
    unsigned short* ob = kvc16 + (size_t)(bh * C_ + c) * (M_ * D_);
#pragma unroll
    for (int ti = 0; ti < 2; ++ti)
#pragma unroll
      for (int j = 0; j < 4; ++j) {
        const int row = rblk + ti * 16 + l16 * 4 + j;  // d
#pragma unroll
        for (int tj = 0; tj < 4; ++tj) {
          const int col = cblk + tj * 16 + l15;  // m
          ob[row * M_ + col] = f2bf(acc2[ti][tj][j]);
        }
      }
  }
}

// Exclusive prefix across chunks. Per chunk, add the EXACT eps terms:
// KV: sc_c*KVE + REPS_*Vsum_c[d];  ks: sc_c*ksE + KEPS_.
__global__ __launch_bounds__(256) void prefix_kernel(
    const unsigned short* __restrict__ kvc16,
    unsigned short* __restrict__ kvp16, float* __restrict__ ksc,
    const float* __restrict__ blockmax, const float* __restrict__ vsum) {
  __shared__ float bm_s[C_];
  __shared__ float sc_s[C_];
  __shared__ float vs_s[2][C_];
  const int bid = blockIdx.x;  // B*H*32
  const int ej = bid & 31, bh = bid >> 5;
  if (threadIdx.x < C_) bm_s[threadIdx.x] = blockmax[bh * C_ + threadIdx.x];
  if (threadIdx.x >= 64 && threadIdx.x < 64 + 2 * C_) {
    const int t = threadIdx.x - 64;
    const int ld = t >> 5, cc = t & 31;  // this block's d rows: ej*2, ej*2+1
    vs_s[ld][cc] = vsum[(size_t)(bh * C_ + cc) * D_ + ej * 2 + ld];
  }
  __syncthreads();
  if (threadIdx.x < C_) {
    float km = -INFINITY;
#pragma unroll
    for (int cc = 0; cc < C_; ++cc) km = fmaxf(km, bm_s[cc]);
    sc_s[threadIdx.x] = expf(bm_s[threadIdx.x] - km);
  }
  __syncthreads();
  const int e = ej * 256 + threadIdx.x;  // element of [D][M]
  const int dl = threadIdx.x >> 7;       // which of the block's 2 d-rows
  float vals[C_];
#pragma unroll
  for (int cc = 0; cc < C_; ++cc)
    vals[cc] = bf2f(kvc16[(size_t)(bh * C_ + cc) * (M_ * D_) + e]) * sc_s[cc] +
               REPS_ * vs_s[dl][cc];
  float run = 0.f;
#pragma unroll
  for (int cc = 0; cc < C_; ++cc) {
    const float t = vals[cc];
    vals[cc] = run;
    run += t;
  }
#pragma unroll
  for (int cc = 0; cc < C_; ++cc)
    kvp16[(size_t)(bh * C_ + cc) * (M_ * D_) + e] = f2bf(vals[cc]);
  if (ej == 0 && threadIdx.x < M_) {
    const int m = threadIdx.x;
    float ks[C_];
#pragma unroll
    for (int cc = 0; cc < C_; ++cc)
      ks[cc] = ksc[(size_t)(bh * C_ + cc) * M_ + m] * sc_s[cc] + KEPS_;
    float rs = 0.f;
#pragma unroll
    for (int cc = 0; cc < C_; ++cc) {
      const float t = ks[cc];
      ks[cc] = rs;
      rs += t;
    }
#pragma unroll
    for (int cc = 0; cc < C_; ++cc)
      ksc[(size_t)(bh * C_ + cc) * M_ + m] = ks[cc];
  }
}

// Intra-chunk MFMA. S_true[t][t'] = sc*SE[t][t'] + REPS_*qsum[t] (unmasked).
__global__ __launch_bounds__(256) void intra_kernel(
    const unsigned short* __restrict__ qp16,
    const unsigned short* __restrict__ kp16,
    const unsigned short* __restrict__ vt16,
    const unsigned short* __restrict__ kvp16, const float* __restrict__ ksp,
    const float* __restrict__ blockmax, float* __restrict__ out) {
  __shared__ __align__(16) unsigned short qp_s[T_][136];
  __shared__ __align__(16) unsigned short kp_s[T_][136];
  __shared__ __align__(16) unsigned short kvp_s[D_][136];
  __shared__ __align__(16) unsigned short S_s[T_][72];
  __shared__ __align__(16) unsigned short vt_s[D_][72];
  __shared__ float ksp_s[M_];
  __shared__ float denp_s[4][T_];
  __shared__ float qsump_s[4][T_];
  __shared__ float den_s[T_];
  __shared__ float bm_s[C_];

  const int bid = blockIdx.x;
  const int c = bid % C_, bh = bid / C_;
  const int b = bh >> 3, h = bh & 7;
  const int tid = threadIdx.x;
  const int w = tid >> 6, lane = tid & 63;
  const int l15 = lane & 15, l16 = lane >> 4;

  const unsigned short* qpt = qp16 + ((size_t)bh * L_ + c * T_) * M_;
  const unsigned short* kpt = kp16 + ((size_t)bh * L_ + c * T_) * M_;
  const unsigned short* kvt = kvp16 + (size_t)(bh * C_ + c) * (M_ * D_);
  const unsigned short* vg = vt16 + (size_t)(bh * C_ + c) * (D_ * T_);

  if (tid < C_) bm_s[tid] = blockmax[bh * C_ + tid];
  for (int i8 = tid; i8 < T_ * 16; i8 += 256) {
    const int r = i8 >> 4, m0 = (i8 & 15) * 8;
    *reinterpret_cast<short8*>(&qp_s[r][m0]) =
        *reinterpret_cast<const short8*>(&qpt[r * M_ + m0]);
    *reinterpret_cast<short8*>(&kp_s[r][m0]) =
        *reinterpret_cast<const short8*>(&kpt[r * M_ + m0]);
    *reinterpret_cast<short8*>(&kvp_s[r][m0]) =
        *reinterpret_cast<const short8*>(&kvt[r * M_ + m0]);
  }
  for (int i8 = tid; i8 < D_ * 8; i8 += 256) {
    const int d = i8 >> 3, t0 = (i8 & 7) * 8;
    *reinterpret_cast<short8*>(&vt_s[d][t0]) =
        *reinterpret_cast<const short8*>(&vg[d * T_ + t0]);
  }
  if (tid < M_) ksp_s[tid] = ksp[(size_t)(bh * C_ + c) * M_ + tid];
  __syncthreads();

  // qsum[t] partials (for the S eps term); each wave covers 32 m-cols
  {
    const int t = lane;
    float p = 0.f;
    for (int m = w * 32; m < w * 32 + 32; ++m) p += bf2f(qp_s[t][m]);
    qsump_s[w][t] = p;
  }
  __syncthreads();

  float km = -INFINITY;
#pragma unroll
  for (int cc = 0; cc < C_; ++cc) km = fmaxf(km, bm_s[cc]);
  const float sc = expf(bm_s[c] - km);

  const int rblk = (w >> 1) * 32, cblk = (w & 1) * 32;
  f32x4 Sacc[2][2];
#pragma unroll
  for (int i = 0; i < 2; ++i)
#pragma unroll
    for (int j = 0; j < 2; ++j) Sacc[i][j] = {0.f, 0.f, 0.f, 0.f};

#pragma unroll
  for (int kk = 0; kk < 4; ++kk) {
    short8 af[2], bf[2];
#pragma unroll
    for (int ti = 0; ti < 2; ++ti)
      af[ti] = *reinterpret_cast<const short8*>(
          &qp_s[rblk + ti * 16 + l15][kk * 32 + l16 * 8]);
#pragma unroll
    for (int tj = 0; tj < 2; ++tj)
      bf[tj] = *reinterpret_cast<const short8*>(
          &kp_s[cblk + tj * 16 + l15][kk * 32 + l16 * 8]);
#pragma unroll
    for (int ti = 0; ti < 2; ++ti)
#pragma unroll
      for (int tj = 0; tj < 2; ++tj)
        Sacc[ti][tj] = __builtin_amdgcn_mfma_f32_16x16x32_bf16(
            af[ti], bf[tj], Sacc[ti][tj], 0, 0, 0);
  }
#pragma unroll
  for (int ti = 0; ti < 2; ++ti)
#pragma unroll
    for (int tj = 0; tj < 2; ++tj)
#pragma unroll
      for (int j = 0; j < 4; ++j) {
        const int row = rblk + ti * 16 + l16 * 4 + j;
        const int col = cblk + tj * 16 + l15;
        const float add = REPS_ * (qsump_s[0][row] + qsump_s[1][row] +
                                   qsump_s[2][row] + qsump_s[3][row]);
        const float sv = (col <= row) ? Sacc[ti][tj][j] * sc + add : 0.f;
        S_s[row][col] = f2bf(sv);
      }
  __syncthreads();

  {
    const int t = lane;
    float p = 0.f;
    if (w == 0) {
      for (int tp = 0; tp < 32; ++tp) p += bf2f(S_s[t][tp]);
    } else if (w == 1) {
      for (int tp = 32; tp < 64; ++tp) p += bf2f(S_s[t][tp]);
    } else if (w == 2) {
      for (int m = 0; m < 64; ++m) p += bf2f(qp_s[t][m]) * ksp_s[m];
    } else {
      for (int m = 64; m < 128; ++m) p += bf2f(qp_s[t][m]) * ksp_s[m];
    }
    denp_s[w][t] = p;
  }
  __syncthreads();
  if (tid < T_)
    den_s[tid] =
        denp_s[0][tid] + denp_s[1][tid] + denp_s[2][tid] + denp_s[3][tid];
  __syncthreads();

  const int dblk = (w & 1) * 32;
  f32x4 Nacc[2][2];
#pragma unroll
  for (int i = 0; i < 2; ++i)
#pragma unroll
    for (int j = 0; j < 2; ++j) Nacc[i][j] = {0.f, 0.f, 0.f, 0.f};

#pragma unroll
  for (int kk = 0; kk < 2; ++kk) {
    short8 af[2], bf[2];
#pragma unroll
    for (int ti = 0; ti < 2; ++ti)
      af[ti] = *reinterpret_cast<const short8*>(
          &S_s[rblk + ti * 16 + l15][kk * 32 + l16 * 8]);
#pragma unroll
    for (int tj = 0; tj < 2; ++tj)
      bf[tj] = *reinterpret_cast<const short8*>(
          &vt_s[dblk + tj * 16 + l15][kk * 32 + l16 * 8]);
#pragma unroll
    for (int ti = 0; ti < 2; ++ti)
#pragma unroll
      for (int tj = 0; tj < 2; ++tj)
        Nacc[ti][tj] = __builtin_amdgcn_mfma_f32_16x16x32_bf16(
            af[ti], bf[tj], Nacc[ti][tj], 0, 0, 0);
  }
#pragma unroll
  for (int kk = 0; kk < 4; ++kk) {
    short8 af[2], bf[2];
#pragma unroll
    for (int ti = 0; ti < 2; ++ti)
      af[ti] = *reinterpret_cast<const short8*>(
          &qp_s[rblk + ti * 16 + l15][kk * 32 + l16 * 8]);
#pragma unroll
    for (int tj = 0; tj < 2; ++tj)
      bf[tj] = *reinterpret_cast<const short8*>(
          &kvp_s[dblk + tj * 16 + l15][kk * 32 + l16 * 8]);
#pragma unroll
    for (int ti = 0; ti < 2; ++ti)
#pragma unroll
      for (int tj = 0; tj < 2; ++tj)
        Nacc[ti][tj] = __builtin_amdgcn_mfma_f32_16x16x32_bf16(
            af[ti], bf[tj], Nacc[ti][tj], 0, 0, 0);
  }

#pragma unroll
  for (int ti = 0; ti < 2; ++ti)
#pragma unroll
    for (int j = 0; j < 4; ++j) {
      const int row = rblk + ti * 16 + l16 * 4 + j;
      const float r = 1.f / den_s[row];
      float* orow = out + ((size_t)(b * L_ + c * T_ + row) * H_ + h) * D_;
#pragma unroll
      for (int tj = 0; tj < 2; ++tj) {
        const int col = dblk + tj * 16 + l15;
        orow[col] = Nacc[ti][tj][j] * r;
      }
    }
}

extern "C" void kernel_launch(void* const* d_in, const int* in_sizes, int n_in,
                              void* d_out, int out_size, void* d_ws,
                              size_t ws_size, hipStream_t stream) {
  const float* q = (const float*)d_in[0];
  const float* k = (const float*)d_in[1];
  const float* v = (const float*)d_in[2];
  const float* P = (const float*)d_in[3];
  float* out = (float*)d_out;

  float* ws = (float*)d_ws;
  float* blockmax = ws;                                   // 512
  float* ksp = blockmax + 512;                            // B*H*C*M = 65536
  float* vsum = ksp + (size_t)B_ * H_ * C_ * M_;          // B*H*C*D = 32768
  unsigned short* qp16 = (unsigned short*)(vsum + (size_t)B_ * H_ * C_ * D_);
  unsigned short* kp16 = qp16 + (size_t)B_ * H_ * L_ * M_;
  unsigned short* kvc16 = kp16 + (size_t)B_ * H_ * L_ * M_;
  unsigned short* kvp16 = kvc16 + (size_t)B_ * H_ * C_ * D_ * M_;
  unsigned short* vt16 = kvp16 + (size_t)B_ * H_ * C_ * D_ * M_;  // B*H*C*D*T

  feat_kernel<<<2 * B_ * H_ * C_, 256, 0, stream>>>(
      q, k, P, v, qp16, kp16, kvc16, ksp, vt16, blockmax, vsum);
  prefix_kernel<<<B_ * H_ * 32, 256, 0, stream>>>(kvc16, kvp16, ksp, blockmax,
                                                  vsum);
  intra_kernel<<<B_ * H_ * C_, 256, 0, stream>>>(qp16, kp16, vt16, kvp16, ksp,
                                                 blockmax, out);
}